// Round 10
// baseline (976.701 us; speedup 1.0000x reference)
//
#include <hip/hip_runtime.h>
#include <hip/hip_cooperative_groups.h>

namespace cg = cooperative_groups;

#define B_GRAPH 128
#define ETOT    (128*4096)
#define N0G     (128*512)
#define HF      128

struct __align__(8) I2 { int x, y; };

struct Args {
    const float *x, *convW, *convb, *bnW, *bnB, *bn7W, *bn7B, *attW, *theta;
    const float *lin1W, *lin1b, *lin2W, *lin2b, *lin3W, *lin3b;
    const int *src0, *dst0;
    int *srcw, *dstw;
    float *wv;
    I2 *csr, *rb2A, *rb2B;
    float *dinvA, *dinvB, *stats0, *stats1, *gacc, *bufGP, *bufH, *t1, *t2, *statsH, *out;
    float ca2, cc2, ca3, cc3;
};

union Smem {
    struct { float Ws[HF*HF]; } gm;                                   // 64 KB (max)
    struct { float red[32*HF]; } pr;                                  // 16 KB
    struct { int cnt[512]; int cur[512]; float dvl[512]; } ini;       // 6 KB
    struct { I2 eds[4096]; I2 rbl[512];
             float dvv[512], p0[512], p1[512], p2[512];
             float ss[512]; int si[512]; float tss[256]; int nid[512];
             int cntN[256], curN[256]; float dvn[256];
             float bna[128], bnb[128]; float red[1024]; } gr;         // ~58 KB
    struct { float gs[256]; float red[256]; } h1;
    struct { float row[128]; float red[128]; } h2;
};

__device__ __forceinline__ void gemm_tile(const float* __restrict__ A, const float* Ws,
                                          float* __restrict__ G, int r0, int cc0){
    float acc[4][8];
    #pragma unroll
    for (int j = 0; j < 4; ++j)
        #pragma unroll
        for (int l = 0; l < 8; ++l) acc[j][l] = 0.f;
    for (int k4 = 0; k4 < 32; ++k4){
        float4 av[4];
        #pragma unroll
        for (int j = 0; j < 4; ++j)
            av[j] = *(const float4*)(A + (size_t)(r0+j)*HF + k4*4);
        #pragma unroll
        for (int kk = 0; kk < 4; ++kk){
            int kl = k4*4 + kk;
            float4 w0 = *(const float4*)(Ws + kl*HF + cc0);
            float4 w1 = *(const float4*)(Ws + kl*HF + cc0 + 64);
            #pragma unroll
            for (int j = 0; j < 4; ++j){
                float aa = reinterpret_cast<const float*>(&av[j])[kk];
                acc[j][0] += aa*w0.x; acc[j][1] += aa*w0.y; acc[j][2] += aa*w0.z; acc[j][3] += aa*w0.w;
                acc[j][4] += aa*w1.x; acc[j][5] += aa*w1.y; acc[j][6] += aa*w1.z; acc[j][7] += aa*w1.w;
            }
        }
    }
    #pragma unroll
    for (int j = 0; j < 4; ++j){
        *(float4*)(G + (size_t)(r0+j)*HF + cc0)      = make_float4(acc[j][0],acc[j][1],acc[j][2],acc[j][3]);
        *(float4*)(G + (size_t)(r0+j)*HF + cc0 + 64) = make_float4(acc[j][4],acc[j][5],acc[j][6],acc[j][7]);
    }
}

__global__ __launch_bounds__(1024) void k_mega(Args a){
    cg::grid_group grid = cg::this_grid();
    __shared__ Smem sm;
    const int b = blockIdx.x, t = threadIdx.x;

    //================ init (blocks 0..127, one graph each) ================
    if (b < B_GRAPH){
        int g = b;
        for (int l = t; l < 512; l += 1024) sm.ini.cnt[l] = 0;
        if (t < 256) a.gacc[g*256 + t] = 0.f;
        if (g == 0 && t < 384) a.statsH[t] = 0.f;
        if (g == 0 && t < 256){ a.stats0[t] = 0.f; a.stats1[t] = 0.f; }
        __syncthreads();
        for (int j = t; j < 4096; j += 1024){
            int e = g*4096 + j;
            int sg = a.src0[e], dg = a.dst0[e];
            a.srcw[e] = sg; a.dstw[e] = dg; a.wv[e] = 1.f;
            atomicAdd(&sm.ini.cnt[dg & 511], 1);
        }
        __syncthreads();
        int c0v = 0, c1v = 0, ps = 0;
        if (t < 256){ c0v = sm.ini.cnt[2*t]; c1v = sm.ini.cnt[2*t+1]; ps = c0v + c1v; sm.ini.cur[t] = ps; }
        __syncthreads();
        for (int off = 1; off < 256; off <<= 1){
            int aa = 0;
            if (t < 256 && t >= off) aa = sm.ini.cur[t-off];
            __syncthreads();
            if (t < 256) sm.ini.cur[t] += aa;
            __syncthreads();
        }
        int beg = 0;
        if (t < 256) beg = sm.ini.cur[t] - ps;
        __syncthreads();
        if (t < 256){ sm.ini.cur[2*t] = beg; sm.ini.cur[2*t+1] = beg + c0v; }
        __syncthreads();
        for (int l = t; l < 512; l += 1024){
            I2 r; r.x = g*4096 + sm.ini.cur[l]; r.y = sm.ini.cnt[l];
            a.rb2A[g*512 + l] = r;
            float dv = rsqrtf((float)sm.ini.cnt[l] + 1.f);
            sm.ini.dvl[l] = dv;
            a.dinvA[g*512 + l] = dv;
        }
        __syncthreads();
        for (int j = t; j < 4096; j += 1024){
            int e = g*4096 + j;
            int sg = a.srcw[e], dl = a.dstw[e] & 511;
            int p = atomicAdd(&sm.ini.cur[dl], 1);
            I2 ed; ed.x = sg; ed.y = __float_as_int(sm.ini.dvl[sg & 511]);
            a.csr[g*4096 + p] = ed;
        }
    }
    grid.sync();

    //================ 5 levels ================
    for (int lev = 0; lev < 5; ++lev){
        const int n = 512 >> lev, Nn = B_GRAPH*n;
        const float* A = lev ? a.bufGP : a.x;
        float* G = lev ? (a.bufGP + (size_t)4*1024*1024) : a.bufGP;
        const float* Wg = a.convW + (size_t)lev*HF*HF;
        const float* cb = a.convb + lev*HF;
        I2* rb_cur = (lev & 1) ? a.rb2B : a.rb2A;
        I2* rb_nxt = (lev & 1) ? a.rb2A : a.rb2B;
        float* dv_cur = (lev & 1) ? a.dinvB : a.dinvA;
        float* dv_nxt = (lev & 1) ? a.dinvA : a.dinvB;
        float* st_cur = (lev & 1) ? a.stats1 : a.stats0;
        float* st_nxt = (lev & 1) ? a.stats0 : a.stats1;

        //---- GEMM (chip-wide, full W in LDS, XCD-aligned tiles) ----
        {
            float4* wd = (float4*)sm.gm.Ws;
            const float4* wsrc = (const float4*)Wg;
            #pragma unroll
            for (int i2 = 0; i2 < 4; ++i2) wd[t + i2*1024] = wsrc[t + i2*1024];
            __syncthreads();
            int sub = t >> 8, t8 = t & 255, tx = t8 & 15, ty = t8 >> 4;
            int cc0 = tx*4;
            if (n >= 64){
                int lt = 3 - lev;                    // log2(tiles per graph)
                int xcd = b & 7, local = (b >> 3)*4 + sub;
                int cmax = (Nn/64) >> 3;             // tiles per xcd slot
                for (int c = local; c < cmax; c += 128){
                    int g = ((c >> lt) << 3) | xcd;
                    int m = c & ((1 << lt) - 1);
                    gemm_tile(A, sm.gm.Ws, G, g*n + m*64 + ty*4, cc0);
                }
            } else {
                for (int tt = b*4 + sub; tt < Nn/64; tt += 1024)
                    gemm_tile(A, sm.gm.Ws, G, tt*64 + ty*4, cc0);
            }
        }
        grid.sync();

        //---- prop + BN stats (chip-wide, XCD-aligned) ----
        {
            int sub = t >> 8, t8 = t & 255;
            int nd = t8 >> 5, f = (t8 & 31)*4;
            float cbv0 = cb[f], cbv1 = cb[f+1], cbv2 = cb[f+2], cbv3 = cb[f+3];
            float sx=0.f,sy=0.f,sz=0.f,sw=0.f, qx=0.f,qy=0.f,qz=0.f,qw=0.f;
            int lb = 6 - lev;
            int xcd = b & 7, local = (b >> 3)*4 + sub;
            int cmax = (Nn/8) >> 3;
            for (int c = local; c < cmax; c += 128){
                int g = ((c >> lb) << 3) | xcd;
                int m = c & ((1 << lb) - 1);
                int v = g*n + m*8 + nd;
                float dv = dv_cur[v];
                float4 y = *(const float4*)(G + (size_t)v*HF + f);
                float ax=0.f,ay=0.f,az=0.f,aw2=0.f;
                I2 rb = rb_cur[v];
                int e1 = rb.x + rb.y;
                for (int j = rb.x; j < e1; ++j){
                    I2 e = a.csr[j];
                    int sN = e.x & (Nn-1);
                    float en = __int_as_float(e.y);
                    float4 h = *(const float4*)(G + (size_t)sN*HF + f);
                    ax += en*h.x; ay += en*h.y; az += en*h.z; aw2 += en*h.w;
                }
                float ox = y.x*dv*dv + dv*ax + cbv0;
                float oy = y.y*dv*dv + dv*ay + cbv1;
                float oz = y.z*dv*dv + dv*az + cbv2;
                float ow = y.w*dv*dv + dv*aw2 + cbv3;
                *(float4*)(a.bufH + (size_t)v*HF + f) = make_float4(ox,oy,oz,ow);
                sx += ox; sy += oy; sz += oz; sw += ow;
                qx += ox*ox; qy += oy*oy; qz += oz*oz; qw += ow*ow;
            }
            int base = (t >> 5)*HF + (t & 31)*4;
            __syncthreads();
            *(float4*)&sm.pr.red[base] = make_float4(sx,sy,sz,sw);
            __syncthreads();
            if (t < 128){
                float accs = 0.f;
                #pragma unroll
                for (int j = 0; j < 32; ++j) accs += sm.pr.red[j*HF + t];
                atomicAdd(&st_cur[t], accs);
            }
            __syncthreads();
            *(float4*)&sm.pr.red[base] = make_float4(qx,qy,qz,qw);
            __syncthreads();
            if (t < 128){
                float accs = 0.f;
                #pragma unroll
                for (int j = 0; j < 32; ++j) accs += sm.pr.red[j*HF + t];
                atomicAdd(&st_cur[128+t], accs);
            }
        }
        grid.sync();

        //---- graph phase (blocks 0..127) ----
        if (b < B_GRAPH){
            int g = b;
            int kk2 = n >> 1;
            float invN = 1.f / (float)Nn;
            const float* gw = a.bnW + lev*HF;
            const float* gb = a.bnB + lev*HF;
            const float* aw = a.attW + lev*HF;
            const float* th = a.theta + lev*4;
            int last = (lev == 4);

            if (t < 256) st_nxt[t] = 0.f;
            if (t < 128){
                float mean = st_cur[t]*invN;
                float var  = st_cur[128+t]*invN - mean*mean;
                float iv   = rsqrtf(var + 1e-5f);
                sm.gr.bna[t] = iv*gw[t];
                sm.gr.bnb[t] = gb[t] - mean*iv*gw[t];
            }
            for (int l = t; l < n; l += 1024){
                I2 rb = rb_cur[g*n + l];
                I2 rr; rr.x = rb.x - g*4096; rr.y = rb.y;
                sm.gr.rbl[l] = rr;
                sm.gr.dvv[l] = dv_cur[g*n + l];
            }
            __syncthreads();
            int medg = sm.gr.rbl[n-1].x + sm.gr.rbl[n-1].y;
            for (int j = t; j < medg; j += 1024){
                I2 e = a.csr[g*4096 + j];
                I2 e2; e2.x = e.x & (n-1); e2.y = e.y;
                sm.gr.eds[j] = e2;
            }
            int lane = t & 63, wid = t >> 6;
            for (int l = wid; l < n; l += 16){
                const float* hp = a.bufH + ((size_t)g*n + l)*HF;
                float a0 = hp[lane], a1 = hp[lane+64];
                float v0 = fmaxf(a0*sm.gr.bna[lane]    + sm.gr.bnb[lane],    0.f) * aw[lane];
                float v1 = fmaxf(a1*sm.gr.bna[lane+64] + sm.gr.bnb[lane+64], 0.f) * aw[lane+64];
                float p = v0 + v1;
                for (int off2 = 32; off2; off2 >>= 1) p += __shfl_down(p, off2);
                if (lane == 0) sm.gr.p0[l] = p;
            }
            __syncthreads();
            for (int l = t; l < n; l += 1024){
                I2 rc = sm.gr.rbl[l];
                float acc = 0.f;
                for (int j = 0; j < rc.y; ++j){
                    I2 e = sm.gr.eds[rc.x + j];
                    acc += __int_as_float(e.y) * sm.gr.p0[e.x];
                }
                float dv = sm.gr.dvv[l];
                sm.gr.p1[l] = 2.f*(sm.gr.p0[l]*dv*dv + dv*acc);
            }
            __syncthreads();
            for (int l = t; l < n; l += 1024){
                I2 rc = sm.gr.rbl[l];
                float acc = 0.f;
                for (int j = 0; j < rc.y; ++j){
                    I2 e = sm.gr.eds[rc.x + j];
                    acc += __int_as_float(e.y) * sm.gr.p1[e.x];
                }
                float dv = sm.gr.dvv[l];
                sm.gr.p2[l] = a.ca2*(sm.gr.p1[l]*dv*dv + dv*acc) + a.cc2*sm.gr.p0[l];
            }
            __syncthreads();
            float t0v = th[0], t1v = th[1], t2c = th[2], t3v = th[3];
            for (int l = t; l < n; l += 1024){
                I2 rc = sm.gr.rbl[l];
                float acc = 0.f;
                for (int j = 0; j < rc.y; ++j){
                    I2 e = sm.gr.eds[rc.x + j];
                    acc += __int_as_float(e.y) * sm.gr.p2[e.x];
                }
                float dv = sm.gr.dvv[l];
                float tv = sm.gr.p2[l]*dv*dv + dv*acc;
                float p3 = a.ca3*tv + a.cc3*sm.gr.p1[l];
                sm.gr.ss[l] = t0v*sm.gr.p0[l] + t1v*sm.gr.p1[l] + t2c*sm.gr.p2[l] + t3v*p3;
                sm.gr.si[l] = l;
            }
            __syncthreads();
            for (int size = 2; size <= n; size <<= 1){
                for (int stride = size >> 1; stride > 0; stride >>= 1){
                    for (int i = t; i < n; i += 1024){
                        int j = i ^ stride;
                        if (j > i){
                            bool asc = ((i & size) == 0);
                            float s1 = sm.gr.ss[i], s2 = sm.gr.ss[j];
                            int   i1 = sm.gr.si[i], i2 = sm.gr.si[j];
                            bool gt = (s1 < s2) || (s1 == s2 && i1 > i2);
                            if (gt == asc){ sm.gr.ss[i] = s2; sm.gr.ss[j] = s1; sm.gr.si[i] = i2; sm.gr.si[j] = i1; }
                        }
                    }
                    __syncthreads();
                }
            }
            for (int l = t; l < n; l += 1024) sm.gr.nid[l] = -1;
            __syncthreads();
            for (int r = t; r < kk2; r += 1024){
                sm.gr.nid[sm.gr.si[r]] = r;
                sm.gr.tss[r] = tanhf(sm.gr.ss[r]);
            }
            __syncthreads();
            {
                int f = t & 127, rl = t >> 7;
                float af = sm.gr.bna[f], bf = sm.gr.bnb[f];
                float mx = -3.4e38f, smv = 0.f;
                for (int r = rl; r < kk2; r += 8){
                    int old = sm.gr.si[r];
                    float hv = a.bufH[((size_t)g*n + old)*HF + f];
                    float v = fmaxf(hv*af + bf, 0.f) * sm.gr.tss[r];
                    a.bufGP[((size_t)g*kk2 + r)*HF + f] = v;
                    mx = fmaxf(mx, v); smv += v;
                }
                sm.gr.red[t] = mx;
                __syncthreads();
                if (t < 512) sm.gr.red[t] = fmaxf(sm.gr.red[t], sm.gr.red[t+512]);
                __syncthreads();
                if (t < 256) sm.gr.red[t] = fmaxf(sm.gr.red[t], sm.gr.red[t+256]);
                __syncthreads();
                if (t < 128) a.gacc[g*256 + t] += fmaxf(sm.gr.red[t], sm.gr.red[t+128]);
                __syncthreads();
                sm.gr.red[t] = smv;
                __syncthreads();
                if (t < 512) sm.gr.red[t] += sm.gr.red[t+512];
                __syncthreads();
                if (t < 256) sm.gr.red[t] += sm.gr.red[t+256];
                __syncthreads();
                if (t < 128) a.gacc[g*256 + 128 + t] += (sm.gr.red[t] + sm.gr.red[t+128]) / (float)kk2;
            }
            if (!last){
                __syncthreads();
                if (t < kk2) sm.gr.cntN[t] = 0;
                __syncthreads();
                for (int j = t; j < 4096; j += 1024){
                    int e = g*4096 + j;
                    float we = a.wv[e];
                    int valid = 0, ns = 0, ndd = 0;
                    if (we > 0.5f){
                        int sl = a.srcw[e] & (n-1);
                        int dl = a.dstw[e] & (n-1);
                        ns = sm.gr.nid[sl]; ndd = sm.gr.nid[dl];
                        valid = (ns >= 0) && (ndd >= 0);
                    }
                    if (valid){
                        a.srcw[e] = g*kk2 + ns; a.dstw[e] = g*kk2 + ndd; a.wv[e] = 1.f;
                        atomicAdd(&sm.gr.cntN[ndd], 1);
                    } else {
                        a.srcw[e] = 0; a.dstw[e] = 0; a.wv[e] = 0.f;
                    }
                }
                __syncthreads();
                int c = (t < 256) ? ((t < kk2) ? sm.gr.cntN[t] : 0) : 0;
                if (t < 256) sm.gr.si[t] = c;
                __syncthreads();
                for (int off = 1; off < 256; off <<= 1){
                    int aa = 0;
                    if (t < 256 && t >= off) aa = sm.gr.si[t-off];
                    __syncthreads();
                    if (t < 256) sm.gr.si[t] += aa;
                    __syncthreads();
                }
                if (t < kk2){
                    int beg = sm.gr.si[t] - c;
                    I2 r; r.x = g*4096 + beg; r.y = c;
                    rb_nxt[g*kk2 + t] = r;
                    float dv = rsqrtf((float)c + 1.f);
                    dv_nxt[g*kk2 + t] = dv;
                    sm.gr.dvn[t] = dv;
                    sm.gr.curN[t] = beg;
                }
                __syncthreads();
                for (int j = t; j < 4096; j += 1024){
                    int e = g*4096 + j;
                    if (a.wv[e] > 0.5f){
                        int sg = a.srcw[e], dl = a.dstw[e] & (kk2-1);
                        int p = atomicAdd(&sm.gr.curN[dl], 1);
                        I2 ed; ed.x = sg; ed.y = __float_as_int(sm.gr.dvn[sg & (kk2-1)]);
                        a.csr[g*4096 + p] = ed;
                    }
                }
            }
        }
        grid.sync();
    }

    //================ head ================
    if (b < B_GRAPH){
        int r = b;
        if (t < 256) sm.h1.gs[t] = a.gacc[r*256 + t];
        __syncthreads();
        if (t < 256){
            int c = t & 127, h = t >> 7;
            float s = 0.f;
            #pragma unroll
            for (int kk = 0; kk < 128; ++kk)
                s += sm.h1.gs[h*128 + kk] * a.lin1W[(h*128 + kk)*128 + c];
            sm.h1.red[t] = s;
        }
        __syncthreads();
        if (t < 128){
            float v = (sm.h1.red[t] + sm.h1.red[t+128]) * 0.2f + a.lin1b[t];
            a.t1[r*128 + t] = v;
            atomicAdd(&a.statsH[t], v);
            atomicAdd(&a.statsH[128+t], v*v);
        }
    }
    grid.sync();
    if (b < B_GRAPH){
        int r = b;
        if (t < 128){
            float mean = a.statsH[t] * (1.f/128.f);
            float var  = a.statsH[128+t]*(1.f/128.f) - mean*mean;
            float iv   = rsqrtf(var + 1e-5f);
            float v = (a.t1[r*128+t] - mean)*iv*a.bnW[5*HF + t] + a.bnB[5*HF + t];
            sm.h2.row[t] = fmaxf(v, 0.f);
        }
        __syncthreads();
        if (t < 128){
            int cc = t & 63, h = t >> 6;
            float s = 0.f;
            #pragma unroll
            for (int kk = 0; kk < 64; ++kk)
                s += sm.h2.row[h*64+kk] * a.lin2W[(h*64+kk)*64 + cc];
            sm.h2.red[t] = s;
        }
        __syncthreads();
        if (t < 64){
            float v = sm.h2.red[t] + sm.h2.red[t+64] + a.lin2b[t];
            a.t2[r*64+t] = v;
            atomicAdd(&a.statsH[256+t], v);
            atomicAdd(&a.statsH[320+t], v*v);
        }
    }
    grid.sync();
    if (b < B_GRAPH && t < 64){
        int r = b;
        float mean = a.statsH[256+t]*(1.f/128.f);
        float var  = a.statsH[320+t]*(1.f/128.f) - mean*mean;
        float iv   = rsqrtf(var + 1e-5f);
        float v = fmaxf((a.t2[r*64+t]-mean)*iv*a.bn7W[t] + a.bn7B[t], 0.f);
        float lg[10];
        #pragma unroll
        for (int j = 0; j < 10; ++j){
            float p = v * a.lin3W[t*10 + j];
            for (int off2 = 32; off2; off2 >>= 1) p += __shfl_down(p, off2);
            lg[j] = p;
        }
        if (t == 0){
            float m = -3.4e38f;
            #pragma unroll
            for (int j = 0; j < 10; ++j){ lg[j] += a.lin3b[j]; m = fmaxf(m, lg[j]); }
            float se = 0.f;
            #pragma unroll
            for (int j = 0; j < 10; ++j) se += expf(lg[j] - m);
            float l = logf(se) + m;
            #pragma unroll
            for (int j = 0; j < 10; ++j) a.out[r*10 + j] = lg[j] - l;
        }
    }
}

extern "C" void kernel_launch(void* const* d_in, const int* in_sizes, int n_in,
                              void* d_out, int out_size, void* d_ws, size_t ws_size,
                              hipStream_t stream){
    char* base = (char*)d_ws;
    size_t off = 0;
    auto take = [&](size_t bytes) -> void* {
        void* p = base + off;
        off = (off + bytes + 255) & ~(size_t)255;
        return p;
    };
    Args a;
    a.x     = (const float*)d_in[0];
    a.convW = (const float*)d_in[1];
    a.convb = (const float*)d_in[2];
    a.bnW   = (const float*)d_in[3];
    a.bnB   = (const float*)d_in[4];
    a.bn7W  = (const float*)d_in[5];
    a.bn7B  = (const float*)d_in[6];
    a.attW  = (const float*)d_in[7];
    a.theta = (const float*)d_in[8];
    a.lin1W = (const float*)d_in[9];
    a.lin1b = (const float*)d_in[10];
    a.lin2W = (const float*)d_in[11];
    a.lin2b = (const float*)d_in[12];
    a.lin3W = (const float*)d_in[13];
    a.lin3b = (const float*)d_in[14];
    a.src0  = (const int*)d_in[15];
    a.dst0  = (const int*)d_in[16];

    a.bufGP = (float*)take((size_t)N0G*HF*4);
    a.bufH  = (float*)take((size_t)N0G*HF*4);
    a.srcw  = (int*)  take((size_t)ETOT*4);
    a.dstw  = (int*)  take((size_t)ETOT*4);
    a.wv    = (float*)take((size_t)ETOT*4);
    a.csr   = (I2*)   take((size_t)ETOT*8);
    a.rb2A  = (I2*)   take((size_t)N0G*8);
    a.rb2B  = (I2*)   take((size_t)N0G*8);
    a.dinvA = (float*)take((size_t)N0G*4);
    a.dinvB = (float*)take((size_t)N0G*4);
    a.stats0= (float*)take(256*4);
    a.stats1= (float*)take(256*4);
    a.gacc  = (float*)take((size_t)B_GRAPH*256*4);
    a.t1    = (float*)take((size_t)B_GRAPH*128*4);
    a.t2    = (float*)take((size_t)B_GRAPH*64*4);
    a.statsH= (float*)take(384*4);
    a.out   = (float*)d_out;

    auto coef = [](int kk, float& ca, float& cc){
        double aj = 1.0, bj = 1.0;
        double c0 = 2.0*kk*(kk+aj+bj)*(2.0*kk+aj+bj-2.0);
        double c1 = (2.0*kk+aj+bj-1.0)*(2.0*kk+aj+bj)*(2.0*kk+aj+bj-2.0);
        double c3 = 2.0*(kk+aj-1.0)*(kk+bj-1.0)*(2.0*kk+aj+bj);
        ca = (float)(c1/c0); cc = (float)(-c3/c0);
    };
    coef(2, a.ca2, a.cc2);
    coef(3, a.ca3, a.cc3);

    void* kp[] = { (void*)&a };
    hipLaunchCooperativeKernel((const void*)k_mega, dim3(256), dim3(1024), kp, 0, stream);
}

// Round 11
// 476.249 us; speedup vs baseline: 2.0508x; 2.0508x over previous
//
#include <hip/hip_runtime.h>
#include <hip/hip_bf16.h>

#define B_GRAPH 128
#define ETOT    (128*4096)
#define N0G     (128*512)
#define HF      128

// ---------------- level-0 init ----------------
__global__ __launch_bounds__(256) void k_init(const int* __restrict__ s_in, const int* __restrict__ d_in_,
                                              int* __restrict__ srcw, int* __restrict__ dstw,
                                              float* __restrict__ wv, int2* __restrict__ csr,
                                              int2* __restrict__ rb2, float* __restrict__ dinvv,
                                              float* __restrict__ gacc, float* __restrict__ statsH,
                                              float* __restrict__ st0, float* __restrict__ st1,
                                              float* __restrict__ st2){
    int g = blockIdx.x, t = threadIdx.x;
    __shared__ int cnt[512];
    __shared__ int cur[512];
    __shared__ float dvl[512];
    for (int l = t; l < 512; l += 256) cnt[l] = 0;
    gacc[g*256 + t] = 0.f;
    if (g == 0){
        statsH[t] = 0.f; if (t < 128) statsH[256+t] = 0.f;
        st0[t] = 0.f; st1[t] = 0.f; st2[t] = 0.f;
    }
    __syncthreads();
    for (int j = t; j < 4096; j += 256){
        int e = g*4096 + j;
        int sg = s_in[e], dg = d_in_[e];
        srcw[e] = sg; dstw[e] = dg; wv[e] = 1.f;
        atomicAdd(&cnt[dg & 511], 1);
    }
    __syncthreads();
    int c0 = cnt[2*t], c1 = cnt[2*t+1];
    int pairsum = c0 + c1;
    cur[t] = pairsum;
    __syncthreads();
    for (int off = 1; off < 256; off <<= 1){
        int a = (t >= off) ? cur[t-off] : 0;
        __syncthreads();
        cur[t] += a;
        __syncthreads();
    }
    int begpair = cur[t] - pairsum;
    __syncthreads();
    cur[2*t]   = begpair;
    cur[2*t+1] = begpair + c0;
    __syncthreads();
    for (int l = t; l < 512; l += 256){
        rb2[g*512 + l] = make_int2(g*4096 + cur[l], cnt[l]);
        float dv = rsqrtf((float)cnt[l] + 1.f);
        dvl[l] = dv;
        dinvv[g*512 + l] = dv;
    }
    __syncthreads();
    for (int j = t; j < 4096; j += 256){
        int e = g*4096 + j;
        int sg = srcw[e], dl = dstw[e] & 511;
        int p = atomicAdd(&cur[dl], 1);
        csr[g*4096 + p] = make_int2(sg, __float_as_int(dvl[sg & 511]));
    }
}

// ---------------- chip-wide GEMM (level 0) ----------------
__global__ __launch_bounds__(256) void k_gemm(const float* __restrict__ A, const float* __restrict__ Wg,
                                              float* __restrict__ C){
    __shared__ float Ws[64*HF];
    int tx = threadIdx.x & 15, ty = threadIdx.x >> 4;
    int r0 = blockIdx.x*64 + ty*4, c0 = tx*4;
    float acc[4][8];
    #pragma unroll
    for (int j=0;j<4;++j)
        #pragma unroll
        for (int l=0;l<8;++l) acc[j][l] = 0.f;
    for (int kh = 0; kh < 2; ++kh){
        __syncthreads();
        {
            float4* d4 = (float4*)Ws;
            const float4* s4 = (const float4*)(Wg + kh*64*HF);
            for (int i = threadIdx.x; i < 64*HF/4; i += 256) d4[i] = s4[i];
        }
        __syncthreads();
        for (int k4 = 0; k4 < 16; ++k4){
            float4 av[4];
            #pragma unroll
            for (int j=0;j<4;++j)
                av[j] = *(const float4*)(A + (size_t)(r0+j)*HF + kh*64 + k4*4);
            #pragma unroll
            for (int kk=0; kk<4; ++kk){
                int kl = k4*4 + kk;
                float4 w0 = *(const float4*)(Ws + kl*HF + c0);
                float4 w1 = *(const float4*)(Ws + kl*HF + c0 + 64);
                #pragma unroll
                for (int j=0;j<4;++j){
                    float a = reinterpret_cast<const float*>(&av[j])[kk];
                    acc[j][0] += a*w0.x; acc[j][1] += a*w0.y; acc[j][2] += a*w0.z; acc[j][3] += a*w0.w;
                    acc[j][4] += a*w1.x; acc[j][5] += a*w1.y; acc[j][6] += a*w1.z; acc[j][7] += a*w1.w;
                }
            }
        }
    }
    #pragma unroll
    for (int j=0;j<4;++j){
        *(float4*)(C + (size_t)(r0+j)*HF + c0)      = make_float4(acc[j][0],acc[j][1],acc[j][2],acc[j][3]);
        *(float4*)(C + (size_t)(r0+j)*HF + c0 + 64) = make_float4(acc[j][4],acc[j][5],acc[j][6],acc[j][7]);
    }
}

// ---------------- chip-wide prop (level 0, XCD swizzle) ----------------
__global__ __launch_bounds__(256) void k_prop(const float* __restrict__ Y, const float* __restrict__ cb,
                                              const int2* __restrict__ rb2, const int2* __restrict__ cp,
                                              const float* __restrict__ dinv,
                                              float* __restrict__ X, int n, int lb, int Nn){
    int xcd = blockIdx.x & 7, c = blockIdx.x >> 3;
    int g = xcd*16 + (c >> lb);
    int m = c & ((1 << lb) - 1);
    int v = g*n + m*8 + (threadIdx.x >> 5);
    int f4 = threadIdx.x & 31;
    float dv = dinv[v];
    float4 y = *(const float4*)(Y + (size_t)v*HF + f4*4);
    float4 acc = make_float4(0.f, 0.f, 0.f, 0.f);
    int2 rb = rb2[v];
    int e0 = rb.x, e1 = rb.x + rb.y;
    for (int j = e0; j < e1; ++j){
        int2 e = cp[j];
        int s = e.x & (Nn - 1);
        float en = __int_as_float(e.y);
        float4 h = *(const float4*)(Y + (size_t)s*HF + f4*4);
        acc.x += en*h.x; acc.y += en*h.y; acc.z += en*h.z; acc.w += en*h.w;
    }
    int f = f4*4;
    acc.x = y.x*dv*dv + dv*acc.x + cb[f];
    acc.y = y.y*dv*dv + dv*acc.y + cb[f+1];
    acc.z = y.z*dv*dv + dv*acc.z + cb[f+2];
    acc.w = y.w*dv*dv + dv*acc.w + cb[f+3];
    *(float4*)(X + (size_t)v*HF + f) = acc;
}

// ---------------- BN stats (level 0) ----------------
__global__ __launch_bounds__(256) void k_bnstats(const float* __restrict__ X, float* __restrict__ stats){
    int c = threadIdx.x & 127, h = threadIdx.x >> 7;
    int r0 = blockIdx.x * 256;
    float s = 0.f, s2 = 0.f;
    for (int r = r0 + h; r < r0 + 256; r += 2){
        float x = X[(size_t)r*HF + c];
        s += x; s2 += x*x;
    }
    __shared__ float l1[256], l2[256];
    l1[threadIdx.x] = s; l2[threadIdx.x] = s2;
    __syncthreads();
    if (threadIdx.x < 128){
        atomicAdd(&stats[c],     l1[threadIdx.x] + l1[threadIdx.x+128]);
        atomicAdd(&stats[128+c], l2[threadIdx.x] + l2[threadIdx.x+128]);
    }
}

// ---------------- mega-fused per-graph kernel + conv tail for next level ----------------
union KSmem {
    struct {
        int2  eds[4096]; int2 rbl[512];
        float dvv[512], p0[512], p1[512], p2[512];
        float ss[512]; int si[512]; float tss[256]; int nid[512];
        int   cntN[256], curN[256]; float dvn[256];
        float bna[128], bnb[128]; float red[1024];
    } gr;                                     // ~58 KB
    struct { float Ws[64*HF]; float red[32*HF]; } cv;   // 48 KB
};

__global__ __launch_bounds__(1024) void k_graph(
    const float* __restrict__ H, const float* __restrict__ stats,
    const float* __restrict__ gw, const float* __restrict__ gb,
    const float* __restrict__ aw, const float* __restrict__ th,
    const int2* __restrict__ rb2, int2* __restrict__ csr, const float* __restrict__ dinv,
    int* __restrict__ srcw, int* __restrict__ dstw, float* __restrict__ wv,
    float* __restrict__ P, float* __restrict__ gacc,
    int2* __restrict__ rb2n, float* __restrict__ dinvn,
    float* __restrict__ stZero, float* __restrict__ stAcc,
    const float* __restrict__ Wnext, const float* __restrict__ cbNext,
    float* __restrict__ Gnext, float* __restrict__ Hnext,
    float invN, float ca2, float cc2, float ca3, float cc3,
    int n, int last)
{
    int g = blockIdx.x, t = threadIdx.x;
    int k = n >> 1;
    __shared__ KSmem sm;

    if (t < 256) stZero[t] = 0.f;
    if (t < 128){
        float mean = stats[t]*invN;
        float var  = stats[128+t]*invN - mean*mean;
        float iv   = rsqrtf(var + 1e-5f);
        sm.gr.bna[t] = iv*gw[t];
        sm.gr.bnb[t] = gb[t] - mean*iv*gw[t];
    }
    for (int l = t; l < n; l += 1024){
        int2 rb = rb2[g*n + l];
        sm.gr.rbl[l] = make_int2(rb.x - g*4096, rb.y);
        sm.gr.dvv[l] = dinv[g*n + l];
    }
    __syncthreads();
    int medg = sm.gr.rbl[n-1].x + sm.gr.rbl[n-1].y;
    for (int j = t; j < medg; j += 1024){
        int2 e = csr[g*4096 + j];
        sm.gr.eds[j] = make_int2(e.x & (n-1), e.y);
    }
    int lane = t & 63, wid = t >> 6;
    for (int l = wid; l < n; l += 16){
        const float* hp = H + ((size_t)g*n + l)*HF;
        float a0 = hp[lane], a1 = hp[lane+64];
        float v0 = fmaxf(a0*sm.gr.bna[lane]    + sm.gr.bnb[lane],    0.f) * aw[lane];
        float v1 = fmaxf(a1*sm.gr.bna[lane+64] + sm.gr.bnb[lane+64], 0.f) * aw[lane+64];
        float p = v0 + v1;
        for (int off = 32; off; off >>= 1) p += __shfl_down(p, off);
        if (lane == 0) sm.gr.p0[l] = p;
    }
    __syncthreads();
    for (int l = t; l < n; l += 1024){
        int2 rc = sm.gr.rbl[l];
        float acc = 0.f;
        for (int j = 0; j < rc.y; ++j){
            int2 e = sm.gr.eds[rc.x + j];
            acc += __int_as_float(e.y) * sm.gr.p0[e.x];
        }
        float dv = sm.gr.dvv[l];
        sm.gr.p1[l] = 2.f*(sm.gr.p0[l]*dv*dv + dv*acc);
    }
    __syncthreads();
    for (int l = t; l < n; l += 1024){
        int2 rc = sm.gr.rbl[l];
        float acc = 0.f;
        for (int j = 0; j < rc.y; ++j){
            int2 e = sm.gr.eds[rc.x + j];
            acc += __int_as_float(e.y) * sm.gr.p1[e.x];
        }
        float dv = sm.gr.dvv[l];
        sm.gr.p2[l] = ca2*(sm.gr.p1[l]*dv*dv + dv*acc) + cc2*sm.gr.p0[l];
    }
    __syncthreads();
    float t0v = th[0], t1v = th[1], t2c = th[2], t3v = th[3];
    for (int l = t; l < n; l += 1024){
        int2 rc = sm.gr.rbl[l];
        float acc = 0.f;
        for (int j = 0; j < rc.y; ++j){
            int2 e = sm.gr.eds[rc.x + j];
            acc += __int_as_float(e.y) * sm.gr.p2[e.x];
        }
        float dv = sm.gr.dvv[l];
        float tv = sm.gr.p2[l]*dv*dv + dv*acc;
        float p3 = ca3*tv + cc3*sm.gr.p1[l];
        sm.gr.ss[l] = t0v*sm.gr.p0[l] + t1v*sm.gr.p1[l] + t2c*sm.gr.p2[l] + t3v*p3;
        sm.gr.si[l] = l;
    }
    __syncthreads();
    for (int size = 2; size <= n; size <<= 1){
        for (int stride = size >> 1; stride > 0; stride >>= 1){
            for (int i = t; i < n; i += 1024){
                int j = i ^ stride;
                if (j > i){
                    bool asc = ((i & size) == 0);
                    float s1 = sm.gr.ss[i], s2 = sm.gr.ss[j];
                    int   i1 = sm.gr.si[i], i2 = sm.gr.si[j];
                    bool gt = (s1 < s2) || (s1 == s2 && i1 > i2);
                    if (gt == asc){ sm.gr.ss[i] = s2; sm.gr.ss[j] = s1; sm.gr.si[i] = i2; sm.gr.si[j] = i1; }
                }
            }
            __syncthreads();
        }
    }
    for (int l = t; l < n; l += 1024) sm.gr.nid[l] = -1;
    __syncthreads();
    for (int r = t; r < k; r += 1024){
        sm.gr.nid[sm.gr.si[r]] = r;
        sm.gr.tss[r] = tanhf(sm.gr.ss[r]);
    }
    __syncthreads();
    {
        int f = t & 127, rl = t >> 7;
        float af = sm.gr.bna[f], bf = sm.gr.bnb[f];
        float mx = -3.4e38f, smv = 0.f;
        for (int r = rl; r < k; r += 8){
            int old = sm.gr.si[r];
            float hv = H[((size_t)g*n + old)*HF + f];
            float v = fmaxf(hv*af + bf, 0.f) * sm.gr.tss[r];
            P[((size_t)g*k + r)*HF + f] = v;
            mx = fmaxf(mx, v); smv += v;
        }
        sm.gr.red[t] = mx;
        __syncthreads();
        if (t < 512) sm.gr.red[t] = fmaxf(sm.gr.red[t], sm.gr.red[t+512]);
        __syncthreads();
        if (t < 256) sm.gr.red[t] = fmaxf(sm.gr.red[t], sm.gr.red[t+256]);
        __syncthreads();
        if (t < 128) gacc[g*256 + t] += fmaxf(sm.gr.red[t], sm.gr.red[t+128]);
        __syncthreads();
        sm.gr.red[t] = smv;
        __syncthreads();
        if (t < 512) sm.gr.red[t] += sm.gr.red[t+512];
        __syncthreads();
        if (t < 256) sm.gr.red[t] += sm.gr.red[t+256];
        __syncthreads();
        if (t < 128) gacc[g*256 + 128 + t] += (sm.gr.red[t] + sm.gr.red[t+128]) / (float)k;
    }
    if (last) return;
    __syncthreads();
    // ---- remap + next-level CSR (block-local) ----
    if (t < k) sm.gr.cntN[t] = 0;
    __syncthreads();
    for (int j = t; j < 4096; j += 1024){
        int e = g*4096 + j;
        float we = wv[e];
        int valid = 0, ns = 0, nd = 0;
        if (we > 0.5f){
            int sl = srcw[e] & (n-1);
            int dl = dstw[e] & (n-1);
            ns = sm.gr.nid[sl]; nd = sm.gr.nid[dl];
            valid = (ns >= 0) && (nd >= 0);
        }
        if (valid){
            srcw[e] = g*k + ns; dstw[e] = g*k + nd; wv[e] = 1.f;
            atomicAdd(&sm.gr.cntN[nd], 1);
        } else {
            srcw[e] = 0; dstw[e] = 0; wv[e] = 0.f;
        }
    }
    __syncthreads();
    int c = (t < 256) ? ((t < k) ? sm.gr.cntN[t] : 0) : 0;
    if (t < 256) sm.gr.si[t] = c;
    __syncthreads();
    for (int off = 1; off < 256; off <<= 1){
        int a = 0;
        if (t < 256 && t >= off) a = sm.gr.si[t-off];
        __syncthreads();
        if (t < 256) sm.gr.si[t] += a;
        __syncthreads();
    }
    if (t < k){
        int beg = sm.gr.si[t] - c;
        rb2n[g*k + t] = make_int2(g*4096 + beg, c);
        float dv = rsqrtf((float)c + 1.f);
        dinvn[g*k + t] = dv;
        sm.gr.dvn[t] = dv;
        sm.gr.curN[t] = beg;
    }
    __syncthreads();
    for (int j = t; j < 4096; j += 1024){
        int e = g*4096 + j;
        if (wv[e] > 0.5f){
            int sg = srcw[e], dl = dstw[e] & (k-1);
            int p = atomicAdd(&sm.gr.curN[dl], 1);
            csr[g*4096 + p] = make_int2(sg, __float_as_int(sm.gr.dvn[sg & (k-1)]));
        }
    }
    __syncthreads();
    // ================ conv tail for level L+1 (all inputs block-local) ================
    int Nn2 = B_GRAPH * k;
    // GEMM: Gnext = P @ Wnext (identical FMA order to k_gemm)
    {
        int sub = t >> 8, t8 = t & 255, tx = t8 & 15, ty = t8 >> 4;
        int cc0 = tx*4;
        int nT = (k + 255) >> 8;
        for (int tile = 0; tile < nT; ++tile){
            int r0 = tile*256 + sub*64 + ty*4;
            bool act = (r0 < k);
            float acc[4][8];
            #pragma unroll
            for (int j=0;j<4;++j)
                #pragma unroll
                for (int l=0;l<8;++l) acc[j][l] = 0.f;
            for (int kh = 0; kh < 2; ++kh){
                __syncthreads();
                {
                    float4* d4 = (float4*)sm.cv.Ws;
                    const float4* s4 = (const float4*)(Wnext + kh*64*HF);
                    #pragma unroll
                    for (int i2 = 0; i2 < 2; ++i2) d4[t + i2*1024] = s4[t + i2*1024];
                }
                __syncthreads();
                if (act){
                    for (int k4 = 0; k4 < 16; ++k4){
                        float4 av[4];
                        #pragma unroll
                        for (int j=0;j<4;++j)
                            av[j] = *(const float4*)(P + ((size_t)g*k + r0 + j)*HF + kh*64 + k4*4);
                        #pragma unroll
                        for (int kk=0; kk<4; ++kk){
                            int kl = k4*4 + kk;
                            float4 w0 = *(const float4*)(sm.cv.Ws + kl*HF + cc0);
                            float4 w1 = *(const float4*)(sm.cv.Ws + kl*HF + cc0 + 64);
                            #pragma unroll
                            for (int j=0;j<4;++j){
                                float aa = reinterpret_cast<const float*>(&av[j])[kk];
                                acc[j][0] += aa*w0.x; acc[j][1] += aa*w0.y; acc[j][2] += aa*w0.z; acc[j][3] += aa*w0.w;
                                acc[j][4] += aa*w1.x; acc[j][5] += aa*w1.y; acc[j][6] += aa*w1.z; acc[j][7] += aa*w1.w;
                            }
                        }
                    }
                }
            }
            if (act){
                #pragma unroll
                for (int j=0;j<4;++j){
                    *(float4*)(Gnext + ((size_t)g*k + r0 + j)*HF + cc0)      = make_float4(acc[j][0],acc[j][1],acc[j][2],acc[j][3]);
                    *(float4*)(Gnext + ((size_t)g*k + r0 + j)*HF + cc0 + 64) = make_float4(acc[j][4],acc[j][5],acc[j][6],acc[j][7]);
                }
            }
        }
    }
    __syncthreads();
    // prop + BN-stats accumulate
    {
        int f = (t & 31)*4;
        float4 s  = make_float4(0.f,0.f,0.f,0.f);
        float4 s2 = make_float4(0.f,0.f,0.f,0.f);
        float cb0 = cbNext[f], cb1 = cbNext[f+1], cb2 = cbNext[f+2], cb3 = cbNext[f+3];
        for (int l = t >> 5; l < k; l += 32){
            int v = g*k + l;
            float dv = dinvn[v];
            float4 y = *(const float4*)(Gnext + (size_t)v*HF + f);
            float4 acc = make_float4(0.f,0.f,0.f,0.f);
            int2 rb = rb2n[v];
            int e1 = rb.x + rb.y;
            for (int j = rb.x; j < e1; ++j){
                int2 e = csr[j];
                int sN = e.x & (Nn2 - 1);
                float en = __int_as_float(e.y);
                float4 h = *(const float4*)(Gnext + (size_t)sN*HF + f);
                acc.x += en*h.x; acc.y += en*h.y; acc.z += en*h.z; acc.w += en*h.w;
            }
            acc.x = y.x*dv*dv + dv*acc.x + cb0;
            acc.y = y.y*dv*dv + dv*acc.y + cb1;
            acc.z = y.z*dv*dv + dv*acc.z + cb2;
            acc.w = y.w*dv*dv + dv*acc.w + cb3;
            *(float4*)(Hnext + (size_t)v*HF + f) = acc;
            s.x += acc.x; s.y += acc.y; s.z += acc.z; s.w += acc.w;
            s2.x += acc.x*acc.x; s2.y += acc.y*acc.y; s2.z += acc.z*acc.z; s2.w += acc.w*acc.w;
        }
        int base = (t >> 5)*HF + f;
        __syncthreads();
        *(float4*)&sm.cv.red[base] = s;
        __syncthreads();
        if (t < 128){
            float a = 0.f;
            #pragma unroll
            for (int j = 0; j < 32; ++j) a += sm.cv.red[j*HF + t];
            atomicAdd(&stAcc[t], a);
        }
        __syncthreads();
        *(float4*)&sm.cv.red[base] = s2;
        __syncthreads();
        if (t < 128){
            float a = 0.f;
            #pragma unroll
            for (int j = 0; j < 32; ++j) a += sm.cv.red[j*HF + t];
            atomicAdd(&stAcc[128+t], a);
        }
    }
}

// ---------------- head ----------------
__global__ __launch_bounds__(256) void k_head1(const float* __restrict__ gacc, const float* __restrict__ W1,
                                               const float* __restrict__ b1, float* __restrict__ t1,
                                               float* __restrict__ sh){
    int r = blockIdx.x;
    int c = threadIdx.x & 127, h = threadIdx.x >> 7;
    __shared__ float gs[256];
    __shared__ float red[256];
    gs[threadIdx.x] = gacc[r*256 + threadIdx.x];
    __syncthreads();
    float s = 0.f;
    #pragma unroll
    for (int kk = 0; kk < 128; ++kk)
        s += gs[h*128 + kk] * W1[(h*128 + kk)*128 + c];
    red[threadIdx.x] = s;
    __syncthreads();
    if (h == 0){
        float v = (red[c] + red[c+128]) * 0.2f + b1[c];
        t1[r*128 + c] = v;
        atomicAdd(&sh[c], v);
        atomicAdd(&sh[128 + c], v*v);
    }
}
__global__ __launch_bounds__(128) void k_head2(const float* __restrict__ t1, const float* __restrict__ gw,
                                               const float* __restrict__ gb, const float* __restrict__ W2,
                                               const float* __restrict__ b2, float* __restrict__ sh,
                                               float* __restrict__ t2){
    int r = blockIdx.x, t = threadIdx.x;
    int cc = t & 63, h = t >> 6;
    __shared__ float row[128];
    __shared__ float red[128];
    {
        float mean = sh[t] * (1.f/128.f);
        float var  = sh[128+t]*(1.f/128.f) - mean*mean;
        float iv   = rsqrtf(var + 1e-5f);
        float v = (t1[r*128+t] - mean)*iv*gw[t] + gb[t];
        row[t] = fmaxf(v, 0.f);
    }
    __syncthreads();
    float s = 0.f;
    #pragma unroll
    for (int kk = 0; kk < 64; ++kk)
        s += row[h*64+kk] * W2[(h*64+kk)*64 + cc];
    red[t] = s;
    __syncthreads();
    if (h == 0){
        float v = red[cc] + red[cc+64] + b2[cc];
        t2[r*64+cc] = v;
        atomicAdd(&sh[256+cc], v);
        atomicAdd(&sh[320+cc], v*v);
    }
}
__global__ __launch_bounds__(64) void k_head3(const float* __restrict__ t2, const float* __restrict__ gw,
                                              const float* __restrict__ gb, const float* __restrict__ W3,
                                              const float* __restrict__ b3, const float* __restrict__ sh,
                                              float* __restrict__ out){
    int r = blockIdx.x, t = threadIdx.x;
    float mean = sh[256+t]*(1.f/128.f);
    float var  = sh[320+t]*(1.f/128.f) - mean*mean;
    float iv   = rsqrtf(var + 1e-5f);
    float v = fmaxf((t2[r*64+t]-mean)*iv*gw[t] + gb[t], 0.f);
    float lg[10];
    #pragma unroll
    for (int j = 0; j < 10; ++j){
        float p = v * W3[t*10 + j];
        for (int off = 32; off; off >>= 1) p += __shfl_down(p, off);
        lg[j] = p;
    }
    if (t == 0){
        float m = -3.4e38f;
        #pragma unroll
        for (int j = 0; j < 10; ++j){ lg[j] += b3[j]; m = fmaxf(m, lg[j]); }
        float se = 0.f;
        #pragma unroll
        for (int j = 0; j < 10; ++j) se += expf(lg[j] - m);
        float l = logf(se) + m;
        #pragma unroll
        for (int j = 0; j < 10; ++j) out[r*10 + j] = lg[j] - l;
    }
}

extern "C" void kernel_launch(void* const* d_in, const int* in_sizes, int n_in,
                              void* d_out, int out_size, void* d_ws, size_t ws_size,
                              hipStream_t stream){
    const float* x     = (const float*)d_in[0];
    const float* convW = (const float*)d_in[1];
    const float* convb = (const float*)d_in[2];
    const float* bnW   = (const float*)d_in[3];
    const float* bnB   = (const float*)d_in[4];
    const float* bn7W  = (const float*)d_in[5];
    const float* bn7B  = (const float*)d_in[6];
    const float* attW  = (const float*)d_in[7];
    const float* theta = (const float*)d_in[8];
    const float* lin1W = (const float*)d_in[9];
    const float* lin1b = (const float*)d_in[10];
    const float* lin2W = (const float*)d_in[11];
    const float* lin2b = (const float*)d_in[12];
    const float* lin3W = (const float*)d_in[13];
    const float* lin3b = (const float*)d_in[14];
    const int*   src0  = (const int*)d_in[15];
    const int*   dst0  = (const int*)d_in[16];

    char* base = (char*)d_ws;
    size_t off = 0;
    auto take = [&](size_t bytes) -> void* {
        void* p = base + off;
        off = (off + bytes + 255) & ~(size_t)255;
        return p;
    };
    float* bufGP = (float*)take((size_t)N0G*HF*4);        // P at base; G(L>=1) at +16MB floats
    float* bufHA = (float*)take((size_t)N0G*HF*4);        // H levels 0,2,4
    float* bufHB = (float*)take((size_t)(N0G/2)*HF*4);    // H levels 1,3
    int*   srcw  = (int*)  take((size_t)ETOT*4);
    int*   dstw  = (int*)  take((size_t)ETOT*4);
    float* w     = (float*)take((size_t)ETOT*4);
    int2*  csr_p = (int2*) take((size_t)ETOT*8);
    int2*  rb2A  = (int2*) take((size_t)N0G*8);
    int2*  rb2B  = (int2*) take((size_t)N0G*8);
    float* dinvA = (float*)take((size_t)N0G*4);
    float* dinvB = (float*)take((size_t)N0G*4);
    float* st[3];
    st[0] = (float*)take(256*4);
    st[1] = (float*)take(256*4);
    st[2] = (float*)take(256*4);
    float* gacc  = (float*)take((size_t)B_GRAPH*256*4);
    float* t1    = (float*)take((size_t)B_GRAPH*128*4);
    float* t2    = (float*)take((size_t)B_GRAPH*64*4);
    float* statsH= (float*)take(384*4);

    auto coef = [](int kk, float& ca, float& cc){
        double a = 1.0, b = 1.0;
        double c0 = 2.0*kk*(kk+a+b)*(2.0*kk+a+b-2.0);
        double c1 = (2.0*kk+a+b-1.0)*(2.0*kk+a+b)*(2.0*kk+a+b-2.0);
        double c3 = 2.0*(kk+a-1.0)*(kk+b-1.0)*(2.0*kk+a+b);
        ca = (float)(c1/c0); cc = (float)(-c3/c0);
    };
    float ca2, cc2, ca3, cc3;
    coef(2, ca2, cc2);
    coef(3, ca3, cc3);

    k_init<<<B_GRAPH, 256, 0, stream>>>(src0, dst0, srcw, dstw, w, csr_p, rb2A, dinvA,
                                        gacc, statsH, st[0], st[1], st[2]);

    float* G = bufGP + (size_t)4*1024*1024;   // G region for levels >= 1 (and level-0 G uses bufGP base? no:)
    // level 0: G must not alias P (P unused at level 0) -> use bufGP base for G0
    k_gemm<<<N0G/64, 256, 0, stream>>>(x, convW, bufGP);
    k_prop<<<N0G/8, 256, 0, stream>>>(bufGP, convb, rb2A, csr_p, dinvA, bufHA, 512, 6, N0G);
    k_bnstats<<<N0G/256, 256, 0, stream>>>(bufHA, st[0]);

    for (int i = 0; i < 5; ++i){
        int n = 512 >> i;
        int Nn = B_GRAPH*n;
        int2*  rb_cur = (i & 1) ? rb2B : rb2A;
        int2*  rb_nxt = (i & 1) ? rb2A : rb2B;
        float* dv_cur = (i & 1) ? dinvB : dinvA;
        float* dv_nxt = (i & 1) ? dinvA : dinvB;
        float* Hcur = (i & 1) ? bufHB : bufHA;
        float* Hnxt = (i & 1) ? bufHA : bufHB;
        int wnext = (i < 4) ? (i + 1) : 4;

        k_graph<<<B_GRAPH, 1024, 0, stream>>>(Hcur, st[i % 3], bnW + i*HF, bnB + i*HF, attW + i*HF,
                                              theta + i*4, rb_cur, csr_p, dv_cur,
                                              srcw, dstw, w, bufGP, gacc, rb_nxt, dv_nxt,
                                              st[(i + 2) % 3], st[(i + 1) % 3],
                                              convW + (size_t)wnext*HF*HF, convb + wnext*HF,
                                              G, Hnxt,
                                              1.0f/(float)Nn, ca2, cc2, ca3, cc3, n, (i == 4) ? 1 : 0);
    }

    k_head1<<<B_GRAPH, 256, 0, stream>>>(gacc, lin1W, lin1b, t1, statsH);
    k_head2<<<B_GRAPH, 128, 0, stream>>>(t1, bnW + 5*HF, bnB + 5*HF, lin2W, lin2b, statsH, t2);
    k_head3<<<B_GRAPH, 64, 0, stream>>>(t2, bn7W, bn7B, lin3W, lin3b, statsH, (float*)d_out);
}

// Round 12
// 443.962 us; speedup vs baseline: 2.2000x; 1.0727x over previous
//
#include <hip/hip_runtime.h>
#include <hip/hip_bf16.h>

#define B_GRAPH 128
#define ETOT    (128*4096)
#define N0G     (128*512)
#define HF      128
// banked stats: [8][256] floats (bank = XCD-ish id) to keep atomics uncontended
#define STSZ    2048

// ---------------- merged: level-0 GEMM (blocks 0..1023) + per-graph init (blocks 1024..1151) ----------------
union IGSmem {
    float Ws[64*HF];                                     // 32 KB (gemm branch)
    struct { int cnt[512]; int cur[512]; float dvl[512]; } ini;
};

__global__ __launch_bounds__(256) void k_init_gemm(
    const float* __restrict__ A, const float* __restrict__ Wg, float* __restrict__ C,
    const int* __restrict__ s_in, const int* __restrict__ d_in_,
    int* __restrict__ srcw, int* __restrict__ dstw, float* __restrict__ wv,
    int2* __restrict__ csr, int2* __restrict__ rb2, float* __restrict__ dinvv,
    float* __restrict__ gacc, float* __restrict__ statsH,
    float* __restrict__ st0, float* __restrict__ st1, float* __restrict__ st2)
{
    __shared__ IGSmem sm;
    int t = threadIdx.x;
    if (blockIdx.x < 1024){
        // ---- GEMM branch (identical FMA order to previous k_gemm) ----
        int tx = t & 15, ty = t >> 4;
        int r0 = blockIdx.x*64 + ty*4, c0 = tx*4;
        float acc[4][8];
        #pragma unroll
        for (int j=0;j<4;++j)
            #pragma unroll
            for (int l=0;l<8;++l) acc[j][l] = 0.f;
        for (int kh = 0; kh < 2; ++kh){
            __syncthreads();
            {
                float4* d4 = (float4*)sm.Ws;
                const float4* s4 = (const float4*)(Wg + kh*64*HF);
                for (int i = t; i < 64*HF/4; i += 256) d4[i] = s4[i];
            }
            __syncthreads();
            for (int k4 = 0; k4 < 16; ++k4){
                float4 av[4];
                #pragma unroll
                for (int j=0;j<4;++j)
                    av[j] = *(const float4*)(A + (size_t)(r0+j)*HF + kh*64 + k4*4);
                #pragma unroll
                for (int kk=0; kk<4; ++kk){
                    int kl = k4*4 + kk;
                    float4 w0 = *(const float4*)(sm.Ws + kl*HF + c0);
                    float4 w1 = *(const float4*)(sm.Ws + kl*HF + c0 + 64);
                    #pragma unroll
                    for (int j=0;j<4;++j){
                        float a = reinterpret_cast<const float*>(&av[j])[kk];
                        acc[j][0] += a*w0.x; acc[j][1] += a*w0.y; acc[j][2] += a*w0.z; acc[j][3] += a*w0.w;
                        acc[j][4] += a*w1.x; acc[j][5] += a*w1.y; acc[j][6] += a*w1.z; acc[j][7] += a*w1.w;
                    }
                }
            }
        }
        #pragma unroll
        for (int j=0;j<4;++j){
            *(float4*)(C + (size_t)(r0+j)*HF + c0)      = make_float4(acc[j][0],acc[j][1],acc[j][2],acc[j][3]);
            *(float4*)(C + (size_t)(r0+j)*HF + c0 + 64) = make_float4(acc[j][4],acc[j][5],acc[j][6],acc[j][7]);
        }
    } else {
        // ---- init branch ----
        int g = blockIdx.x - 1024;
        for (int l = t; l < 512; l += 256) sm.ini.cnt[l] = 0;
        gacc[g*256 + t] = 0.f;
        if (g == 0){
            if (t < 256){ statsH[t] = 0.f; if (t < 128) statsH[256+t] = 0.f; }
            for (int i = t; i < STSZ; i += 256){ st0[i] = 0.f; st1[i] = 0.f; st2[i] = 0.f; }
        }
        __syncthreads();
        for (int j = t; j < 4096; j += 256){
            int e = g*4096 + j;
            int sg = s_in[e], dg = d_in_[e];
            srcw[e] = sg; dstw[e] = dg; wv[e] = 1.f;
            atomicAdd(&sm.ini.cnt[dg & 511], 1);
        }
        __syncthreads();
        int c0 = sm.ini.cnt[2*t], c1 = sm.ini.cnt[2*t+1];
        int pairsum = c0 + c1;
        sm.ini.cur[t] = pairsum;
        __syncthreads();
        for (int off = 1; off < 256; off <<= 1){
            int a = (t >= off) ? sm.ini.cur[t-off] : 0;
            __syncthreads();
            sm.ini.cur[t] += a;
            __syncthreads();
        }
        int begpair = sm.ini.cur[t] - pairsum;
        __syncthreads();
        sm.ini.cur[2*t]   = begpair;
        sm.ini.cur[2*t+1] = begpair + c0;
        __syncthreads();
        for (int l = t; l < 512; l += 256){
            rb2[g*512 + l] = make_int2(g*4096 + sm.ini.cur[l], sm.ini.cnt[l]);
            float dv = rsqrtf((float)sm.ini.cnt[l] + 1.f);
            sm.ini.dvl[l] = dv;
            dinvv[g*512 + l] = dv;
        }
        __syncthreads();
        for (int j = t; j < 4096; j += 256){
            int e = g*4096 + j;
            int sg = srcw[e], dl = dstw[e] & 511;
            int p = atomicAdd(&sm.ini.cur[dl], 1);
            csr[g*4096 + p] = make_int2(sg, __float_as_int(sm.ini.dvl[sg & 511]));
        }
    }
}

// ---------------- chip-wide prop + banked BN stats (level 0, XCD swizzle) ----------------
__global__ __launch_bounds__(256) void k_prop_stats(const float* __restrict__ Y, const float* __restrict__ cb,
                                                    const int2* __restrict__ rb2, const int2* __restrict__ cp,
                                                    const float* __restrict__ dinv,
                                                    float* __restrict__ X, float* __restrict__ st,
                                                    int n, int lb, int Nn){
    __shared__ float rs[1024], rq[1024];
    int xcd = blockIdx.x & 7, c = blockIdx.x >> 3;
    int g = xcd*16 + (c >> lb);
    int m = c & ((1 << lb) - 1);
    int nd = threadIdx.x >> 5;
    int v = g*n + m*8 + nd;
    int f4 = threadIdx.x & 31;
    float dv = dinv[v];
    float4 y = *(const float4*)(Y + (size_t)v*HF + f4*4);
    float4 acc = make_float4(0.f, 0.f, 0.f, 0.f);
    int2 rb = rb2[v];
    int e0 = rb.x, e1 = rb.x + rb.y;
    for (int j = e0; j < e1; ++j){
        int2 e = cp[j];
        int s = e.x & (Nn - 1);
        float en = __int_as_float(e.y);
        float4 h = *(const float4*)(Y + (size_t)s*HF + f4*4);
        acc.x += en*h.x; acc.y += en*h.y; acc.z += en*h.z; acc.w += en*h.w;
    }
    int f = f4*4;
    acc.x = y.x*dv*dv + dv*acc.x + cb[f];
    acc.y = y.y*dv*dv + dv*acc.y + cb[f+1];
    acc.z = y.z*dv*dv + dv*acc.z + cb[f+2];
    acc.w = y.w*dv*dv + dv*acc.w + cb[f+3];
    *(float4*)(X + (size_t)v*HF + f) = acc;
    *(float4*)&rs[nd*HF + f] = acc;
    *(float4*)&rq[nd*HF + f] = make_float4(acc.x*acc.x, acc.y*acc.y, acc.z*acc.z, acc.w*acc.w);
    __syncthreads();
    if (threadIdx.x < 128){
        int tt = threadIdx.x;
        float s = 0.f, q = 0.f;
        #pragma unroll
        for (int j = 0; j < 8; ++j){ s += rs[j*HF + tt]; q += rq[j*HF + tt]; }
        atomicAdd(&st[xcd*256 + tt], s);
        atomicAdd(&st[xcd*256 + 128 + tt], q);
    }
}

// ---------------- mega-fused per-graph kernel + conv tail + (L4) head1 tail ----------------
union KSmem {
    struct {
        int2  eds[4096]; int2 rbl[512];
        float dvv[512], p0[512], p1[512], p2[512];
        float ss[512]; int si[512]; float tss[256]; int nid[512];
        int   cntN[256], curN[256]; float dvn[256];
        float bna[128], bnb[128]; float red[1024];
    } gr;
    struct { float Ws[64*HF]; float red[32*HF]; } cv;
};

__global__ __launch_bounds__(1024) void k_graph(
    const float* __restrict__ H, const float* __restrict__ stats,
    const float* __restrict__ gw, const float* __restrict__ gb,
    const float* __restrict__ aw, const float* __restrict__ th,
    const int2* __restrict__ rb2, int2* __restrict__ csr, const float* __restrict__ dinv,
    int* __restrict__ srcw, int* __restrict__ dstw, float* __restrict__ wv,
    float* __restrict__ P, float* __restrict__ gacc,
    int2* __restrict__ rb2n, float* __restrict__ dinvn,
    float* __restrict__ stZero, float* __restrict__ stAcc,
    const float* __restrict__ Wnext, const float* __restrict__ cbNext,
    float* __restrict__ Gnext, float* __restrict__ Hnext,
    const float* __restrict__ lin1W, const float* __restrict__ lin1b,
    float* __restrict__ t1g, float* __restrict__ statsH,
    float invN, float ca2, float cc2, float ca3, float cc3,
    int n, int last)
{
    int g = blockIdx.x, t = threadIdx.x;
    int k = n >> 1;
    __shared__ KSmem sm;

    for (int i = t; i < STSZ; i += 1024) stZero[i] = 0.f;
    if (t < 128){
        float s = 0.f, q = 0.f;
        #pragma unroll
        for (int b2 = 0; b2 < 8; ++b2){ s += stats[b2*256 + t]; q += stats[b2*256 + 128 + t]; }
        float mean = s*invN;
        float var  = q*invN - mean*mean;
        float iv   = rsqrtf(var + 1e-5f);
        sm.gr.bna[t] = iv*gw[t];
        sm.gr.bnb[t] = gb[t] - mean*iv*gw[t];
    }
    for (int l = t; l < n; l += 1024){
        int2 rb = rb2[g*n + l];
        sm.gr.rbl[l] = make_int2(rb.x - g*4096, rb.y);
        sm.gr.dvv[l] = dinv[g*n + l];
    }
    __syncthreads();
    int medg = sm.gr.rbl[n-1].x + sm.gr.rbl[n-1].y;
    for (int j = t; j < medg; j += 1024){
        int2 e = csr[g*4096 + j];
        sm.gr.eds[j] = make_int2(e.x & (n-1), e.y);
    }
    int lane = t & 63, wid = t >> 6;
    for (int l = wid; l < n; l += 16){
        const float* hp = H + ((size_t)g*n + l)*HF;
        float a0 = hp[lane], a1 = hp[lane+64];
        float v0 = fmaxf(a0*sm.gr.bna[lane]    + sm.gr.bnb[lane],    0.f) * aw[lane];
        float v1 = fmaxf(a1*sm.gr.bna[lane+64] + sm.gr.bnb[lane+64], 0.f) * aw[lane+64];
        float p = v0 + v1;
        for (int off = 32; off; off >>= 1) p += __shfl_down(p, off);
        if (lane == 0) sm.gr.p0[l] = p;
    }
    __syncthreads();
    for (int l = t; l < n; l += 1024){
        int2 rc = sm.gr.rbl[l];
        float acc = 0.f;
        for (int j = 0; j < rc.y; ++j){
            int2 e = sm.gr.eds[rc.x + j];
            acc += __int_as_float(e.y) * sm.gr.p0[e.x];
        }
        float dv = sm.gr.dvv[l];
        sm.gr.p1[l] = 2.f*(sm.gr.p0[l]*dv*dv + dv*acc);
    }
    __syncthreads();
    for (int l = t; l < n; l += 1024){
        int2 rc = sm.gr.rbl[l];
        float acc = 0.f;
        for (int j = 0; j < rc.y; ++j){
            int2 e = sm.gr.eds[rc.x + j];
            acc += __int_as_float(e.y) * sm.gr.p1[e.x];
        }
        float dv = sm.gr.dvv[l];
        sm.gr.p2[l] = ca2*(sm.gr.p1[l]*dv*dv + dv*acc) + cc2*sm.gr.p0[l];
    }
    __syncthreads();
    float t0v = th[0], t1v = th[1], t2c = th[2], t3v = th[3];
    for (int l = t; l < n; l += 1024){
        int2 rc = sm.gr.rbl[l];
        float acc = 0.f;
        for (int j = 0; j < rc.y; ++j){
            int2 e = sm.gr.eds[rc.x + j];
            acc += __int_as_float(e.y) * sm.gr.p2[e.x];
        }
        float dv = sm.gr.dvv[l];
        float tv = sm.gr.p2[l]*dv*dv + dv*acc;
        float p3 = ca3*tv + cc3*sm.gr.p1[l];
        sm.gr.ss[l] = t0v*sm.gr.p0[l] + t1v*sm.gr.p1[l] + t2c*sm.gr.p2[l] + t3v*p3;
        sm.gr.si[l] = l;
    }
    __syncthreads();
    for (int size = 2; size <= n; size <<= 1){
        for (int stride = size >> 1; stride > 0; stride >>= 1){
            for (int i = t; i < n; i += 1024){
                int j = i ^ stride;
                if (j > i){
                    bool asc = ((i & size) == 0);
                    float s1 = sm.gr.ss[i], s2 = sm.gr.ss[j];
                    int   i1 = sm.gr.si[i], i2 = sm.gr.si[j];
                    bool gt = (s1 < s2) || (s1 == s2 && i1 > i2);
                    if (gt == asc){ sm.gr.ss[i] = s2; sm.gr.ss[j] = s1; sm.gr.si[i] = i2; sm.gr.si[j] = i1; }
                }
            }
            __syncthreads();
        }
    }
    for (int l = t; l < n; l += 1024) sm.gr.nid[l] = -1;
    __syncthreads();
    for (int r = t; r < k; r += 1024){
        sm.gr.nid[sm.gr.si[r]] = r;
        sm.gr.tss[r] = tanhf(sm.gr.ss[r]);
    }
    __syncthreads();
    {
        int f = t & 127, rl = t >> 7;
        float af = sm.gr.bna[f], bf = sm.gr.bnb[f];
        float mx = -3.4e38f, smv = 0.f;
        for (int r = rl; r < k; r += 8){
            int old = sm.gr.si[r];
            float hv = H[((size_t)g*n + old)*HF + f];
            float v = fmaxf(hv*af + bf, 0.f) * sm.gr.tss[r];
            P[((size_t)g*k + r)*HF + f] = v;
            mx = fmaxf(mx, v); smv += v;
        }
        sm.gr.red[t] = mx;
        __syncthreads();
        if (t < 512) sm.gr.red[t] = fmaxf(sm.gr.red[t], sm.gr.red[t+512]);
        __syncthreads();
        if (t < 256) sm.gr.red[t] = fmaxf(sm.gr.red[t], sm.gr.red[t+256]);
        __syncthreads();
        if (t < 128) gacc[g*256 + t] += fmaxf(sm.gr.red[t], sm.gr.red[t+128]);
        __syncthreads();
        sm.gr.red[t] = smv;
        __syncthreads();
        if (t < 512) sm.gr.red[t] += sm.gr.red[t+512];
        __syncthreads();
        if (t < 256) sm.gr.red[t] += sm.gr.red[t+256];
        __syncthreads();
        if (t < 128) gacc[g*256 + 128 + t] += (sm.gr.red[t] + sm.gr.red[t+128]) / (float)k;
    }
    if (last){
        // ======== head1 tail: t1 row g = gacc[g]@W1*0.2+b1 ; statsH atomics ========
        __syncthreads();
        int c = t & 127, h = t >> 7;            // h in 0..7, k-chunks of 32
        float s = 0.f;
        int k0 = h*32;
        #pragma unroll
        for (int kk = 0; kk < 32; ++kk)
            s += gacc[g*256 + k0 + kk] * lin1W[(k0 + kk)*128 + c];
        sm.gr.red[t] = s;
        __syncthreads();
        if (t < 512) sm.gr.red[t] += sm.gr.red[t+512];
        __syncthreads();
        if (t < 256) sm.gr.red[t] += sm.gr.red[t+256];
        __syncthreads();
        if (t < 128){
            float v = (sm.gr.red[t] + sm.gr.red[t+128]) * 0.2f + lin1b[t];
            t1g[g*128 + t] = v;
            atomicAdd(&statsH[t], v);
            atomicAdd(&statsH[128+t], v*v);
        }
        return;
    }
    __syncthreads();
    // ---- remap + next-level CSR ----
    if (t < k) sm.gr.cntN[t] = 0;
    __syncthreads();
    for (int j = t; j < 4096; j += 1024){
        int e = g*4096 + j;
        float we = wv[e];
        int valid = 0, ns = 0, nd = 0;
        if (we > 0.5f){
            int sl = srcw[e] & (n-1);
            int dl = dstw[e] & (n-1);
            ns = sm.gr.nid[sl]; nd = sm.gr.nid[dl];
            valid = (ns >= 0) && (nd >= 0);
        }
        if (valid){
            srcw[e] = g*k + ns; dstw[e] = g*k + nd; wv[e] = 1.f;
            atomicAdd(&sm.gr.cntN[nd], 1);
        } else {
            srcw[e] = 0; dstw[e] = 0; wv[e] = 0.f;
        }
    }
    __syncthreads();
    int c = (t < 256) ? ((t < k) ? sm.gr.cntN[t] : 0) : 0;
    if (t < 256) sm.gr.si[t] = c;
    __syncthreads();
    for (int off = 1; off < 256; off <<= 1){
        int a = 0;
        if (t < 256 && t >= off) a = sm.gr.si[t-off];
        __syncthreads();
        if (t < 256) sm.gr.si[t] += a;
        __syncthreads();
    }
    if (t < k){
        int beg = sm.gr.si[t] - c;
        rb2n[g*k + t] = make_int2(g*4096 + beg, c);
        float dv = rsqrtf((float)c + 1.f);
        dinvn[g*k + t] = dv;
        sm.gr.dvn[t] = dv;
        sm.gr.curN[t] = beg;
    }
    __syncthreads();
    for (int j = t; j < 4096; j += 1024){
        int e = g*4096 + j;
        if (wv[e] > 0.5f){
            int sg = srcw[e], dl = dstw[e] & (k-1);
            int p = atomicAdd(&sm.gr.curN[dl], 1);
            csr[g*4096 + p] = make_int2(sg, __float_as_int(sm.gr.dvn[sg & (k-1)]));
        }
    }
    __syncthreads();
    // ======== conv tail for level L+1 ========
    int Nn2 = B_GRAPH * k;
    {
        int sub = t >> 8, t8 = t & 255, tx = t8 & 15, ty = t8 >> 4;
        int cc0 = tx*4;
        int nT = (k + 255) >> 8;
        for (int tile = 0; tile < nT; ++tile){
            int r0 = tile*256 + sub*64 + ty*4;
            bool act = (r0 < k);
            float acc[4][8];
            #pragma unroll
            for (int j=0;j<4;++j)
                #pragma unroll
                for (int l=0;l<8;++l) acc[j][l] = 0.f;
            for (int kh = 0; kh < 2; ++kh){
                __syncthreads();
                {
                    float4* d4 = (float4*)sm.cv.Ws;
                    const float4* s4 = (const float4*)(Wnext + kh*64*HF);
                    #pragma unroll
                    for (int i2 = 0; i2 < 2; ++i2) d4[t + i2*1024] = s4[t + i2*1024];
                }
                __syncthreads();
                if (act){
                    for (int k4 = 0; k4 < 16; ++k4){
                        float4 av[4];
                        #pragma unroll
                        for (int j=0;j<4;++j)
                            av[j] = *(const float4*)(P + ((size_t)g*k + r0 + j)*HF + kh*64 + k4*4);
                        #pragma unroll
                        for (int kk=0; kk<4; ++kk){
                            int kl = k4*4 + kk;
                            float4 w0 = *(const float4*)(sm.cv.Ws + kl*HF + cc0);
                            float4 w1 = *(const float4*)(sm.cv.Ws + kl*HF + cc0 + 64);
                            #pragma unroll
                            for (int j=0;j<4;++j){
                                float aa = reinterpret_cast<const float*>(&av[j])[kk];
                                acc[j][0] += aa*w0.x; acc[j][1] += aa*w0.y; acc[j][2] += aa*w0.z; acc[j][3] += aa*w0.w;
                                acc[j][4] += aa*w1.x; acc[j][5] += aa*w1.y; acc[j][6] += aa*w1.z; acc[j][7] += aa*w1.w;
                            }
                        }
                    }
                }
            }
            if (act){
                #pragma unroll
                for (int j=0;j<4;++j){
                    *(float4*)(Gnext + ((size_t)g*k + r0 + j)*HF + cc0)      = make_float4(acc[j][0],acc[j][1],acc[j][2],acc[j][3]);
                    *(float4*)(Gnext + ((size_t)g*k + r0 + j)*HF + cc0 + 64) = make_float4(acc[j][4],acc[j][5],acc[j][6],acc[j][7]);
                }
            }
        }
    }
    __syncthreads();
    {
        int f = (t & 31)*4;
        float4 s  = make_float4(0.f,0.f,0.f,0.f);
        float4 s2 = make_float4(0.f,0.f,0.f,0.f);
        float cb0 = cbNext[f], cb1 = cbNext[f+1], cb2 = cbNext[f+2], cb3 = cbNext[f+3];
        for (int l = t >> 5; l < k; l += 32){
            int v = g*k + l;
            float dv = dinvn[v];
            float4 y = *(const float4*)(Gnext + (size_t)v*HF + f);
            float4 acc = make_float4(0.f,0.f,0.f,0.f);
            int2 rb = rb2n[v];
            int e1 = rb.x + rb.y;
            for (int j = rb.x; j < e1; ++j){
                int2 e = csr[j];
                int sN = e.x & (Nn2 - 1);
                float en = __int_as_float(e.y);
                float4 h = *(const float4*)(Gnext + (size_t)sN*HF + f);
                acc.x += en*h.x; acc.y += en*h.y; acc.z += en*h.z; acc.w += en*h.w;
            }
            acc.x = y.x*dv*dv + dv*acc.x + cb0;
            acc.y = y.y*dv*dv + dv*acc.y + cb1;
            acc.z = y.z*dv*dv + dv*acc.z + cb2;
            acc.w = y.w*dv*dv + dv*acc.w + cb3;
            *(float4*)(Hnext + (size_t)v*HF + f) = acc;
            s.x += acc.x; s.y += acc.y; s.z += acc.z; s.w += acc.w;
            s2.x += acc.x*acc.x; s2.y += acc.y*acc.y; s2.z += acc.z*acc.z; s2.w += acc.w*acc.w;
        }
        int base = (t >> 5)*HF + f;
        __syncthreads();
        *(float4*)&sm.cv.red[base] = s;
        __syncthreads();
        if (t < 128){
            float a = 0.f;
            #pragma unroll
            for (int j = 0; j < 32; ++j) a += sm.cv.red[j*HF + t];
            atomicAdd(&stAcc[(g & 7)*256 + t], a);
        }
        __syncthreads();
        *(float4*)&sm.cv.red[base] = s2;
        __syncthreads();
        if (t < 128){
            float a = 0.f;
            #pragma unroll
            for (int j = 0; j < 32; ++j) a += sm.cv.red[j*HF + t];
            atomicAdd(&stAcc[(g & 7)*256 + 128 + t], a);
        }
    }
}

// ---------------- head tail kernels ----------------
__global__ __launch_bounds__(128) void k_head2(const float* __restrict__ t1, const float* __restrict__ gw,
                                               const float* __restrict__ gb, const float* __restrict__ W2,
                                               const float* __restrict__ b2, float* __restrict__ sh,
                                               float* __restrict__ t2){
    int r = blockIdx.x, t = threadIdx.x;
    int cc = t & 63, h = t >> 6;
    __shared__ float row[128];
    __shared__ float red[128];
    {
        float mean = sh[t] * (1.f/128.f);
        float var  = sh[128+t]*(1.f/128.f) - mean*mean;
        float iv   = rsqrtf(var + 1e-5f);
        float v = (t1[r*128+t] - mean)*iv*gw[t] + gb[t];
        row[t] = fmaxf(v, 0.f);
    }
    __syncthreads();
    float s = 0.f;
    #pragma unroll
    for (int kk = 0; kk < 64; ++kk)
        s += row[h*64+kk] * W2[(h*64+kk)*64 + cc];
    red[t] = s;
    __syncthreads();
    if (h == 0){
        float v = red[cc] + red[cc+64] + b2[cc];
        t2[r*64+cc] = v;
        atomicAdd(&sh[256+cc], v);
        atomicAdd(&sh[320+cc], v*v);
    }
}
__global__ __launch_bounds__(64) void k_head3(const float* __restrict__ t2, const float* __restrict__ gw,
                                              const float* __restrict__ gb, const float* __restrict__ W3,
                                              const float* __restrict__ b3, const float* __restrict__ sh,
                                              float* __restrict__ out){
    int r = blockIdx.x, t = threadIdx.x;
    float mean = sh[256+t]*(1.f/128.f);
    float var  = sh[320+t]*(1.f/128.f) - mean*mean;
    float iv   = rsqrtf(var + 1e-5f);
    float v = fmaxf((t2[r*64+t]-mean)*iv*gw[t] + gb[t], 0.f);
    float lg[10];
    #pragma unroll
    for (int j = 0; j < 10; ++j){
        float p = v * W3[t*10 + j];
        for (int off = 32; off; off >>= 1) p += __shfl_down(p, off);
        lg[j] = p;
    }
    if (t == 0){
        float m = -3.4e38f;
        #pragma unroll
        for (int j = 0; j < 10; ++j){ lg[j] += b3[j]; m = fmaxf(m, lg[j]); }
        float se = 0.f;
        #pragma unroll
        for (int j = 0; j < 10; ++j) se += expf(lg[j] - m);
        float l = logf(se) + m;
        #pragma unroll
        for (int j = 0; j < 10; ++j) out[r*10 + j] = lg[j] - l;
    }
}

extern "C" void kernel_launch(void* const* d_in, const int* in_sizes, int n_in,
                              void* d_out, int out_size, void* d_ws, size_t ws_size,
                              hipStream_t stream){
    const float* x     = (const float*)d_in[0];
    const float* convW = (const float*)d_in[1];
    const float* convb = (const float*)d_in[2];
    const float* bnW   = (const float*)d_in[3];
    const float* bnB   = (const float*)d_in[4];
    const float* bn7W  = (const float*)d_in[5];
    const float* bn7B  = (const float*)d_in[6];
    const float* attW  = (const float*)d_in[7];
    const float* theta = (const float*)d_in[8];
    const float* lin1W = (const float*)d_in[9];
    const float* lin1b = (const float*)d_in[10];
    const float* lin2W = (const float*)d_in[11];
    const float* lin2b = (const float*)d_in[12];
    const float* lin3W = (const float*)d_in[13];
    const float* lin3b = (const float*)d_in[14];
    const int*   src0  = (const int*)d_in[15];
    const int*   dst0  = (const int*)d_in[16];

    char* base = (char*)d_ws;
    size_t off = 0;
    auto take = [&](size_t bytes) -> void* {
        void* p = base + off;
        off = (off + bytes + 255) & ~(size_t)255;
        return p;
    };
    float* bufGP = (float*)take((size_t)N0G*HF*4);
    float* bufHA = (float*)take((size_t)N0G*HF*4);
    float* bufHB = (float*)take((size_t)(N0G/2)*HF*4);
    int*   srcw  = (int*)  take((size_t)ETOT*4);
    int*   dstw  = (int*)  take((size_t)ETOT*4);
    float* w     = (float*)take((size_t)ETOT*4);
    int2*  csr_p = (int2*) take((size_t)ETOT*8);
    int2*  rb2A  = (int2*) take((size_t)N0G*8);
    int2*  rb2B  = (int2*) take((size_t)N0G*8);
    float* dinvA = (float*)take((size_t)N0G*4);
    float* dinvB = (float*)take((size_t)N0G*4);
    float* st[3];
    st[0] = (float*)take(STSZ*4);
    st[1] = (float*)take(STSZ*4);
    st[2] = (float*)take(STSZ*4);
    float* gacc  = (float*)take((size_t)B_GRAPH*256*4);
    float* t1    = (float*)take((size_t)B_GRAPH*128*4);
    float* t2    = (float*)take((size_t)B_GRAPH*64*4);
    float* statsH= (float*)take(384*4);

    auto coef = [](int kk, float& ca, float& cc){
        double a = 1.0, b = 1.0;
        double c0 = 2.0*kk*(kk+a+b)*(2.0*kk+a+b-2.0);
        double c1 = (2.0*kk+a+b-1.0)*(2.0*kk+a+b)*(2.0*kk+a+b-2.0);
        double c3 = 2.0*(kk+a-1.0)*(kk+b-1.0)*(2.0*kk+a+b);
        ca = (float)(c1/c0); cc = (float)(-c3/c0);
    };
    float ca2, cc2, ca3, cc3;
    coef(2, ca2, cc2);
    coef(3, ca3, cc3);

    // merged init + level-0 GEMM (independent work, disjoint block ranges)
    k_init_gemm<<<1024 + B_GRAPH, 256, 0, stream>>>(x, convW, bufGP,
                                                    src0, dst0, srcw, dstw, w, csr_p, rb2A, dinvA,
                                                    gacc, statsH, st[0], st[1], st[2]);
    // level-0 prop + banked BN stats
    k_prop_stats<<<N0G/8, 256, 0, stream>>>(bufGP, convb, rb2A, csr_p, dinvA, bufHA, st[0], 512, 6, N0G);

    float* G = bufGP + (size_t)4*1024*1024;   // G region for levels >= 1

    for (int i = 0; i < 5; ++i){
        int n = 512 >> i;
        int Nn = B_GRAPH*n;
        int2*  rb_cur = (i & 1) ? rb2B : rb2A;
        int2*  rb_nxt = (i & 1) ? rb2A : rb2B;
        float* dv_cur = (i & 1) ? dinvB : dinvA;
        float* dv_nxt = (i & 1) ? dinvA : dinvB;
        float* Hcur = (i & 1) ? bufHB : bufHA;
        float* Hnxt = (i & 1) ? bufHA : bufHB;
        int wnext = (i < 4) ? (i + 1) : 4;

        k_graph<<<B_GRAPH, 1024, 0, stream>>>(Hcur, st[i % 3], bnW + i*HF, bnB + i*HF, attW + i*HF,
                                              theta + i*4, rb_cur, csr_p, dv_cur,
                                              srcw, dstw, w, bufGP, gacc, rb_nxt, dv_nxt,
                                              st[(i + 2) % 3], st[(i + 1) % 3],
                                              convW + (size_t)wnext*HF*HF, convb + wnext*HF,
                                              G, Hnxt,
                                              lin1W, lin1b, t1, statsH,
                                              1.0f/(float)Nn, ca2, cc2, ca3, cc3, n, (i == 4) ? 1 : 0);
    }

    k_head2<<<B_GRAPH, 128, 0, stream>>>(t1, bnW + 5*HF, bnB + 5*HF, lin2W, lin2b, statsH, t2);
    k_head3<<<B_GRAPH, 64, 0, stream>>>(t2, bn7W, bn7B, lin3W, lin3b, statsH, (float*)d_out);
}

// Round 13
// 402.897 us; speedup vs baseline: 2.4242x; 1.1019x over previous
//
#include <hip/hip_runtime.h>
#include <hip/hip_bf16.h>

#define B_GRAPH 128
#define ETOT    (128*4096)
#define N0G     (128*512)
#define HF      128
// banked stats: [8][256] floats (bank = XCD-ish id) to keep atomics uncontended
#define STSZ    2048

// ---------------- merged: level-0 GEMM (blocks 0..1023) + per-graph init (blocks 1024..1151) ----------------
union IGSmem {
    float Ws[64*HF];                                     // 32 KB (gemm branch)
    struct { int cnt[512]; int cur[512]; float dvl[512]; } ini;
};

__global__ __launch_bounds__(256) void k_init_gemm(
    const float* __restrict__ A, const float* __restrict__ Wg, float* __restrict__ C,
    const int* __restrict__ s_in, const int* __restrict__ d_in_,
    int* __restrict__ srcw, int* __restrict__ dstw, float* __restrict__ wv,
    int2* __restrict__ csr, int2* __restrict__ rb2, float* __restrict__ dinvv,
    float* __restrict__ gacc, float* __restrict__ statsH,
    float* __restrict__ st0, float* __restrict__ st1, float* __restrict__ st2)
{
    __shared__ IGSmem sm;
    int t = threadIdx.x;
    if (blockIdx.x < 1024){
        int tx = t & 15, ty = t >> 4;
        int r0 = blockIdx.x*64 + ty*4, c0 = tx*4;
        float acc[4][8];
        #pragma unroll
        for (int j=0;j<4;++j)
            #pragma unroll
            for (int l=0;l<8;++l) acc[j][l] = 0.f;
        for (int kh = 0; kh < 2; ++kh){
            __syncthreads();
            {
                float4* d4 = (float4*)sm.Ws;
                const float4* s4 = (const float4*)(Wg + kh*64*HF);
                for (int i = t; i < 64*HF/4; i += 256) d4[i] = s4[i];
            }
            __syncthreads();
            for (int k4 = 0; k4 < 16; ++k4){
                float4 av[4];
                #pragma unroll
                for (int j=0;j<4;++j)
                    av[j] = *(const float4*)(A + (size_t)(r0+j)*HF + kh*64 + k4*4);
                #pragma unroll
                for (int kk=0; kk<4; ++kk){
                    int kl = k4*4 + kk;
                    float4 w0 = *(const float4*)(sm.Ws + kl*HF + c0);
                    float4 w1 = *(const float4*)(sm.Ws + kl*HF + c0 + 64);
                    #pragma unroll
                    for (int j=0;j<4;++j){
                        float a = reinterpret_cast<const float*>(&av[j])[kk];
                        acc[j][0] += a*w0.x; acc[j][1] += a*w0.y; acc[j][2] += a*w0.z; acc[j][3] += a*w0.w;
                        acc[j][4] += a*w1.x; acc[j][5] += a*w1.y; acc[j][6] += a*w1.z; acc[j][7] += a*w1.w;
                    }
                }
            }
        }
        #pragma unroll
        for (int j=0;j<4;++j){
            *(float4*)(C + (size_t)(r0+j)*HF + c0)      = make_float4(acc[j][0],acc[j][1],acc[j][2],acc[j][3]);
            *(float4*)(C + (size_t)(r0+j)*HF + c0 + 64) = make_float4(acc[j][4],acc[j][5],acc[j][6],acc[j][7]);
        }
    } else {
        int g = blockIdx.x - 1024;
        for (int l = t; l < 512; l += 256) sm.ini.cnt[l] = 0;
        gacc[g*256 + t] = 0.f;
        if (g == 0){
            if (t < 256){ statsH[t] = 0.f; if (t < 128) statsH[256+t] = 0.f; }
            for (int i = t; i < STSZ; i += 256){ st0[i] = 0.f; st1[i] = 0.f; st2[i] = 0.f; }
        }
        __syncthreads();
        for (int j = t; j < 4096; j += 256){
            int e = g*4096 + j;
            int sg = s_in[e], dg = d_in_[e];
            srcw[e] = sg; dstw[e] = dg; wv[e] = 1.f;
            atomicAdd(&sm.ini.cnt[dg & 511], 1);
        }
        __syncthreads();
        int c0 = sm.ini.cnt[2*t], c1 = sm.ini.cnt[2*t+1];
        int pairsum = c0 + c1;
        sm.ini.cur[t] = pairsum;
        __syncthreads();
        for (int off = 1; off < 256; off <<= 1){
            int a = (t >= off) ? sm.ini.cur[t-off] : 0;
            __syncthreads();
            sm.ini.cur[t] += a;
            __syncthreads();
        }
        int begpair = sm.ini.cur[t] - pairsum;
        __syncthreads();
        sm.ini.cur[2*t]   = begpair;
        sm.ini.cur[2*t+1] = begpair + c0;
        __syncthreads();
        for (int l = t; l < 512; l += 256){
            rb2[g*512 + l] = make_int2(g*4096 + sm.ini.cur[l], sm.ini.cnt[l]);
            float dv = rsqrtf((float)sm.ini.cnt[l] + 1.f);
            sm.ini.dvl[l] = dv;
            dinvv[g*512 + l] = dv;
        }
        __syncthreads();
        for (int j = t; j < 4096; j += 256){
            int e = g*4096 + j;
            int sg = srcw[e], dl = dstw[e] & 511;
            int p = atomicAdd(&sm.ini.cur[dl], 1);
            csr[g*4096 + p] = make_int2(sg, __float_as_int(sm.ini.dvl[sg & 511]));
        }
    }
}

// ---------------- chip-wide prop + banked BN stats (level 0, XCD swizzle) ----------------
__global__ __launch_bounds__(256) void k_prop_stats(const float* __restrict__ Y, const float* __restrict__ cb,
                                                    const int2* __restrict__ rb2, const int2* __restrict__ cp,
                                                    const float* __restrict__ dinv,
                                                    float* __restrict__ X, float* __restrict__ st,
                                                    int n, int lb, int Nn){
    __shared__ float rs[1024], rq[1024];
    int xcd = blockIdx.x & 7, c = blockIdx.x >> 3;
    int g = xcd*16 + (c >> lb);
    int m = c & ((1 << lb) - 1);
    int nd = threadIdx.x >> 5;
    int v = g*n + m*8 + nd;
    int f4 = threadIdx.x & 31;
    float dv = dinv[v];
    float4 y = *(const float4*)(Y + (size_t)v*HF + f4*4);
    float4 acc = make_float4(0.f, 0.f, 0.f, 0.f);
    int2 rb = rb2[v];
    int e0 = rb.x, e1 = rb.x + rb.y;
    for (int j = e0; j < e1; ++j){
        int2 e = cp[j];
        int s = e.x & (Nn - 1);
        float en = __int_as_float(e.y);
        float4 h = *(const float4*)(Y + (size_t)s*HF + f4*4);
        acc.x += en*h.x; acc.y += en*h.y; acc.z += en*h.z; acc.w += en*h.w;
    }
    int f = f4*4;
    acc.x = y.x*dv*dv + dv*acc.x + cb[f];
    acc.y = y.y*dv*dv + dv*acc.y + cb[f+1];
    acc.z = y.z*dv*dv + dv*acc.z + cb[f+2];
    acc.w = y.w*dv*dv + dv*acc.w + cb[f+3];
    *(float4*)(X + (size_t)v*HF + f) = acc;
    *(float4*)&rs[nd*HF + f] = acc;
    *(float4*)&rq[nd*HF + f] = make_float4(acc.x*acc.x, acc.y*acc.y, acc.z*acc.z, acc.w*acc.w);
    __syncthreads();
    if (threadIdx.x < 128){
        int tt = threadIdx.x;
        float s = 0.f, q = 0.f;
        #pragma unroll
        for (int j = 0; j < 8; ++j){ s += rs[j*HF + tt]; q += rq[j*HF + tt]; }
        atomicAdd(&st[xcd*256 + tt], s);
        atomicAdd(&st[xcd*256 + 128 + tt], q);
    }
}

// ---------------- mega-fused per-graph kernel + conv tail + (L4) head1 tail ----------------
union __align__(16) KSmem {
    struct {
        int2  eds[4096]; int2 rbl[512];
        float dvv[512], p0[512], p1[512], p2[512];
        float ss[512]; int si[512]; float tss[256]; int nid[512];
        int   cntN[256], curN[256]; float dvn[256];
        float bna[128], bnb[128]; float red[1024]; float awl[128];
    } gr;
    struct { float Ws[64*HF]; float red[32*HF]; } cv;
};

__global__ __launch_bounds__(1024) void k_graph(
    const float* __restrict__ H, const float* __restrict__ stats,
    const float* __restrict__ gw, const float* __restrict__ gb,
    const float* __restrict__ aw, const float* __restrict__ th,
    const int2* __restrict__ rb2, int2* __restrict__ csr, const float* __restrict__ dinv,
    int* __restrict__ srcw, int* __restrict__ dstw, float* __restrict__ wv,
    float* __restrict__ P, float* __restrict__ gacc,
    int2* __restrict__ rb2n, float* __restrict__ dinvn,
    float* __restrict__ stZero, float* __restrict__ stAcc,
    const float* __restrict__ Wnext, const float* __restrict__ cbNext,
    float* __restrict__ Gnext, float* __restrict__ Hnext,
    const float* __restrict__ lin1W, const float* __restrict__ lin1b,
    float* __restrict__ t1g, float* __restrict__ statsH,
    float invN, float ca2, float cc2, float ca3, float cc3,
    int n, int last)
{
    int g = blockIdx.x, t = threadIdx.x;
    int k = n >> 1;
    __shared__ KSmem sm;

    if (t < 256) stZero[(g & 7)*256 + t] = 0.f;   // each bank zeroed (redundantly by 16 blocks; accumulated only next dispatch)
    if (t < 128){
        float s = 0.f, q = 0.f;
        #pragma unroll
        for (int b2 = 0; b2 < 8; ++b2){ s += stats[b2*256 + t]; q += stats[b2*256 + 128 + t]; }
        float mean = s*invN;
        float var  = q*invN - mean*mean;
        float iv   = rsqrtf(var + 1e-5f);
        sm.gr.bna[t] = iv*gw[t];
        sm.gr.bnb[t] = gb[t] - mean*iv*gw[t];
        sm.gr.awl[t] = aw[t];
    }
    for (int l = t; l < n; l += 1024){
        int2 rb = rb2[g*n + l];
        sm.gr.rbl[l] = make_int2(rb.x - g*4096, rb.y);
        sm.gr.dvv[l] = dinv[g*n + l];
    }
    __syncthreads();
    int medg = sm.gr.rbl[n-1].x + sm.gr.rbl[n-1].y;
    for (int j = t; j < medg; j += 1024){
        int2 e = csr[g*4096 + j];
        sm.gr.eds[j] = make_int2(e.x & (n-1), e.y);
    }
    // ---- s0: 2 threads per node, float4 loads (vectorized; all loads independent) ----
    {
        int l = t >> 1, h = t & 1;
        float part = 0.f;
        if (l < n){
            const float* hp = H + ((size_t)g*n + l)*HF + h*64;
            #pragma unroll
            for (int j = 0; j < 16; ++j){
                float4 v = *(const float4*)(hp + j*4);
                int f = h*64 + j*4;
                float4 a4 = *(const float4*)&sm.gr.bna[f];
                float4 b4 = *(const float4*)&sm.gr.bnb[f];
                float4 w4 = *(const float4*)&sm.gr.awl[f];
                part += fmaxf(v.x*a4.x + b4.x, 0.f)*w4.x
                      + fmaxf(v.y*a4.y + b4.y, 0.f)*w4.y
                      + fmaxf(v.z*a4.z + b4.z, 0.f)*w4.z
                      + fmaxf(v.w*a4.w + b4.w, 0.f)*w4.w;
            }
        }
        sm.gr.red[t] = part;
    }
    __syncthreads();
    for (int l = t; l < n; l += 1024) sm.gr.p0[l] = sm.gr.red[2*l] + sm.gr.red[2*l+1];
    __syncthreads();
    for (int l = t; l < n; l += 1024){
        int2 rc = sm.gr.rbl[l];
        float acc = 0.f;
        for (int j = 0; j < rc.y; ++j){
            int2 e = sm.gr.eds[rc.x + j];
            acc += __int_as_float(e.y) * sm.gr.p0[e.x];
        }
        float dv = sm.gr.dvv[l];
        sm.gr.p1[l] = 2.f*(sm.gr.p0[l]*dv*dv + dv*acc);
    }
    __syncthreads();
    for (int l = t; l < n; l += 1024){
        int2 rc = sm.gr.rbl[l];
        float acc = 0.f;
        for (int j = 0; j < rc.y; ++j){
            int2 e = sm.gr.eds[rc.x + j];
            acc += __int_as_float(e.y) * sm.gr.p1[e.x];
        }
        float dv = sm.gr.dvv[l];
        sm.gr.p2[l] = ca2*(sm.gr.p1[l]*dv*dv + dv*acc) + cc2*sm.gr.p0[l];
    }
    __syncthreads();
    float t0v = th[0], t1v = th[1], t2c = th[2], t3v = th[3];
    for (int l = t; l < n; l += 1024){
        int2 rc = sm.gr.rbl[l];
        float acc = 0.f;
        for (int j = 0; j < rc.y; ++j){
            int2 e = sm.gr.eds[rc.x + j];
            acc += __int_as_float(e.y) * sm.gr.p2[e.x];
        }
        float dv = sm.gr.dvv[l];
        float tv = sm.gr.p2[l]*dv*dv + dv*acc;
        float p3 = ca3*tv + cc3*sm.gr.p1[l];
        sm.gr.ss[l] = t0v*sm.gr.p0[l] + t1v*sm.gr.p1[l] + t2c*sm.gr.p2[l] + t3v*p3;
        sm.gr.si[l] = l;
    }
    __syncthreads();
    for (int size = 2; size <= n; size <<= 1){
        for (int stride = size >> 1; stride > 0; stride >>= 1){
            for (int i = t; i < n; i += 1024){
                int j = i ^ stride;
                if (j > i){
                    bool asc = ((i & size) == 0);
                    float s1 = sm.gr.ss[i], s2 = sm.gr.ss[j];
                    int   i1 = sm.gr.si[i], i2 = sm.gr.si[j];
                    bool gt = (s1 < s2) || (s1 == s2 && i1 > i2);
                    if (gt == asc){ sm.gr.ss[i] = s2; sm.gr.ss[j] = s1; sm.gr.si[i] = i2; sm.gr.si[j] = i1; }
                }
            }
            __syncthreads();
        }
    }
    for (int l = t; l < n; l += 1024) sm.gr.nid[l] = -1;
    __syncthreads();
    for (int r = t; r < k; r += 1024){
        sm.gr.nid[sm.gr.si[r]] = r;
        sm.gr.tss[r] = tanhf(sm.gr.ss[r]);
    }
    __syncthreads();
    // ---- gather (BN+ReLU+tanh scale) + readout, float4 throughout ----
    {
        int f4 = t & 31, rl = t >> 5;          // 32 row-groups
        int f = f4*4;
        float4 a4 = *(const float4*)&sm.gr.bna[f];
        float4 b4 = *(const float4*)&sm.gr.bnb[f];
        float4 mx = make_float4(-3.4e38f,-3.4e38f,-3.4e38f,-3.4e38f);
        float4 smv = make_float4(0.f,0.f,0.f,0.f);
        for (int r = rl; r < k; r += 32){
            int old = sm.gr.si[r];
            float4 hv = *(const float4*)(H + ((size_t)g*n + old)*HF + f);
            float ts = sm.gr.tss[r];
            float4 v;
            v.x = fmaxf(hv.x*a4.x + b4.x, 0.f)*ts;
            v.y = fmaxf(hv.y*a4.y + b4.y, 0.f)*ts;
            v.z = fmaxf(hv.z*a4.z + b4.z, 0.f)*ts;
            v.w = fmaxf(hv.w*a4.w + b4.w, 0.f)*ts;
            *(float4*)(P + ((size_t)g*k + r)*HF + f) = v;
            mx.x = fmaxf(mx.x, v.x); mx.y = fmaxf(mx.y, v.y);
            mx.z = fmaxf(mx.z, v.z); mx.w = fmaxf(mx.w, v.w);
            smv.x += v.x; smv.y += v.y; smv.z += v.z; smv.w += v.w;
        }
        float* scr = (float*)sm.gr.eds;        // 8 KB scratch (eds dead after pvec phases)
        *(float4*)&scr[rl*128 + f]        = mx;
        *(float4*)&scr[4096 + rl*128 + f] = smv;
        __syncthreads();
        if (t < 128){
            float m = -3.4e38f, s = 0.f;
            #pragma unroll
            for (int j = 0; j < 32; ++j){
                m = fmaxf(m, scr[j*128 + t]);
                s += scr[4096 + j*128 + t];
            }
            gacc[g*256 + t] += m;
            gacc[g*256 + 128 + t] += s / (float)k;
        }
    }
    if (last){
        // ======== head1 tail ========
        __syncthreads();
        int c = t & 127, h = t >> 7;
        float s = 0.f;
        int k0 = h*32;
        #pragma unroll
        for (int kk = 0; kk < 32; ++kk)
            s += gacc[g*256 + k0 + kk] * lin1W[(k0 + kk)*128 + c];
        sm.gr.red[t] = s;
        __syncthreads();
        if (t < 512) sm.gr.red[t] += sm.gr.red[t+512];
        __syncthreads();
        if (t < 256) sm.gr.red[t] += sm.gr.red[t+256];
        __syncthreads();
        if (t < 128){
            float v = (sm.gr.red[t] + sm.gr.red[t+128]) * 0.2f + lin1b[t];
            t1g[g*128 + t] = v;
            atomicAdd(&statsH[t], v);
            atomicAdd(&statsH[128+t], v*v);
        }
        return;
    }
    __syncthreads();
    // ---- remap + next-level CSR ----
    if (t < k) sm.gr.cntN[t] = 0;
    __syncthreads();
    for (int j = t; j < 4096; j += 1024){
        int e = g*4096 + j;
        float we = wv[e];
        int valid = 0, ns = 0, nd = 0;
        if (we > 0.5f){
            int sl = srcw[e] & (n-1);
            int dl = dstw[e] & (n-1);
            ns = sm.gr.nid[sl]; nd = sm.gr.nid[dl];
            valid = (ns >= 0) && (nd >= 0);
        }
        if (valid){
            srcw[e] = g*k + ns; dstw[e] = g*k + nd; wv[e] = 1.f;
            atomicAdd(&sm.gr.cntN[nd], 1);
        } else {
            srcw[e] = 0; dstw[e] = 0; wv[e] = 0.f;
        }
    }
    __syncthreads();
    int c = (t < 256) ? ((t < k) ? sm.gr.cntN[t] : 0) : 0;
    if (t < 256) sm.gr.si[t] = c;
    __syncthreads();
    for (int off = 1; off < 256; off <<= 1){
        int a = 0;
        if (t < 256 && t >= off) a = sm.gr.si[t-off];
        __syncthreads();
        if (t < 256) sm.gr.si[t] += a;
        __syncthreads();
    }
    if (t < k){
        int beg = sm.gr.si[t] - c;
        rb2n[g*k + t] = make_int2(g*4096 + beg, c);
        float dv = rsqrtf((float)c + 1.f);
        dinvn[g*k + t] = dv;
        sm.gr.dvn[t] = dv;
        sm.gr.curN[t] = beg;
    }
    __syncthreads();
    for (int j = t; j < 4096; j += 1024){
        int e = g*4096 + j;
        if (wv[e] > 0.5f){
            int sg = srcw[e], dl = dstw[e] & (k-1);
            int p = atomicAdd(&sm.gr.curN[dl], 1);
            csr[g*4096 + p] = make_int2(sg, __float_as_int(sm.gr.dvn[sg & (k-1)]));
        }
    }
    __syncthreads();
    // ======== conv tail for level L+1 ========
    int Nn2 = B_GRAPH * k;
    {
        int sub = t >> 8, t8 = t & 255, tx = t8 & 15, ty = t8 >> 4;
        int cc0 = tx*4;
        int nT = (k + 255) >> 8;
        for (int tile = 0; tile < nT; ++tile){
            int r0 = tile*256 + sub*64 + ty*4;
            bool act = (r0 < k);
            float acc[4][8];
            #pragma unroll
            for (int j=0;j<4;++j)
                #pragma unroll
                for (int l=0;l<8;++l) acc[j][l] = 0.f;
            for (int kh = 0; kh < 2; ++kh){
                __syncthreads();
                {
                    float4* d4 = (float4*)sm.cv.Ws;
                    const float4* s4 = (const float4*)(Wnext + kh*64*HF);
                    #pragma unroll
                    for (int i2 = 0; i2 < 2; ++i2) d4[t + i2*1024] = s4[t + i2*1024];
                }
                __syncthreads();
                if (act){
                    for (int k4 = 0; k4 < 16; ++k4){
                        float4 av[4];
                        #pragma unroll
                        for (int j=0;j<4;++j)
                            av[j] = *(const float4*)(P + ((size_t)g*k + r0 + j)*HF + kh*64 + k4*4);
                        #pragma unroll
                        for (int kk=0; kk<4; ++kk){
                            int kl = k4*4 + kk;
                            float4 w0 = *(const float4*)(sm.cv.Ws + kl*HF + cc0);
                            float4 w1 = *(const float4*)(sm.cv.Ws + kl*HF + cc0 + 64);
                            #pragma unroll
                            for (int j=0;j<4;++j){
                                float aa = reinterpret_cast<const float*>(&av[j])[kk];
                                acc[j][0] += aa*w0.x; acc[j][1] += aa*w0.y; acc[j][2] += aa*w0.z; acc[j][3] += aa*w0.w;
                                acc[j][4] += aa*w1.x; acc[j][5] += aa*w1.y; acc[j][6] += aa*w1.z; acc[j][7] += aa*w1.w;
                            }
                        }
                    }
                }
            }
            if (act){
                #pragma unroll
                for (int j=0;j<4;++j){
                    *(float4*)(Gnext + ((size_t)g*k + r0 + j)*HF + cc0)      = make_float4(acc[j][0],acc[j][1],acc[j][2],acc[j][3]);
                    *(float4*)(Gnext + ((size_t)g*k + r0 + j)*HF + cc0 + 64) = make_float4(acc[j][4],acc[j][5],acc[j][6],acc[j][7]);
                }
            }
        }
    }
    __syncthreads();
    {
        int f = (t & 31)*4;
        float4 s  = make_float4(0.f,0.f,0.f,0.f);
        float4 s2 = make_float4(0.f,0.f,0.f,0.f);
        float cb0 = cbNext[f], cb1 = cbNext[f+1], cb2 = cbNext[f+2], cb3 = cbNext[f+3];
        for (int l = t >> 5; l < k; l += 32){
            int v = g*k + l;
            float dv = dinvn[v];
            float4 y = *(const float4*)(Gnext + (size_t)v*HF + f);
            float4 acc = make_float4(0.f,0.f,0.f,0.f);
            int2 rb = rb2n[v];
            int e1 = rb.x + rb.y;
            for (int j = rb.x; j < e1; ++j){
                int2 e = csr[j];
                int sN = e.x & (Nn2 - 1);
                float en = __int_as_float(e.y);
                float4 h = *(const float4*)(Gnext + (size_t)sN*HF + f);
                acc.x += en*h.x; acc.y += en*h.y; acc.z += en*h.z; acc.w += en*h.w;
            }
            acc.x = y.x*dv*dv + dv*acc.x + cb0;
            acc.y = y.y*dv*dv + dv*acc.y + cb1;
            acc.z = y.z*dv*dv + dv*acc.z + cb2;
            acc.w = y.w*dv*dv + dv*acc.w + cb3;
            *(float4*)(Hnext + (size_t)v*HF + f) = acc;
            s.x += acc.x; s.y += acc.y; s.z += acc.z; s.w += acc.w;
            s2.x += acc.x*acc.x; s2.y += acc.y*acc.y; s2.z += acc.z*acc.z; s2.w += acc.w*acc.w;
        }
        int base = (t >> 5)*HF + f;
        __syncthreads();
        *(float4*)&sm.cv.red[base] = s;
        __syncthreads();
        if (t < 128){
            float a = 0.f;
            #pragma unroll
            for (int j = 0; j < 32; ++j) a += sm.cv.red[j*HF + t];
            atomicAdd(&stAcc[(g & 7)*256 + t], a);
        }
        __syncthreads();
        *(float4*)&sm.cv.red[base] = s2;
        __syncthreads();
        if (t < 128){
            float a = 0.f;
            #pragma unroll
            for (int j = 0; j < 32; ++j) a += sm.cv.red[j*HF + t];
            atomicAdd(&stAcc[(g & 7)*256 + 128 + t], a);
        }
    }
}

// ---------------- head tail kernels ----------------
__global__ __launch_bounds__(128) void k_head2(const float* __restrict__ t1, const float* __restrict__ gw,
                                               const float* __restrict__ gb, const float* __restrict__ W2,
                                               const float* __restrict__ b2, float* __restrict__ sh,
                                               float* __restrict__ t2){
    int r = blockIdx.x, t = threadIdx.x;
    int cc = t & 63, h = t >> 6;
    __shared__ float row[128];
    __shared__ float red[128];
    {
        float mean = sh[t] * (1.f/128.f);
        float var  = sh[128+t]*(1.f/128.f) - mean*mean;
        float iv   = rsqrtf(var + 1e-5f);
        float v = (t1[r*128+t] - mean)*iv*gw[t] + gb[t];
        row[t] = fmaxf(v, 0.f);
    }
    __syncthreads();
    float s = 0.f;
    #pragma unroll
    for (int kk = 0; kk < 64; ++kk)
        s += row[h*64+kk] * W2[(h*64+kk)*64 + cc];
    red[t] = s;
    __syncthreads();
    if (h == 0){
        float v = red[cc] + red[cc+64] + b2[cc];
        t2[r*64+cc] = v;
        atomicAdd(&sh[256+cc], v);
        atomicAdd(&sh[320+cc], v*v);
    }
}
__global__ __launch_bounds__(64) void k_head3(const float* __restrict__ t2, const float* __restrict__ gw,
                                              const float* __restrict__ gb, const float* __restrict__ W3,
                                              const float* __restrict__ b3, const float* __restrict__ sh,
                                              float* __restrict__ out){
    int r = blockIdx.x, t = threadIdx.x;
    float mean = sh[256+t]*(1.f/128.f);
    float var  = sh[320+t]*(1.f/128.f) - mean*mean;
    float iv   = rsqrtf(var + 1e-5f);
    float v = fmaxf((t2[r*64+t]-mean)*iv*gw[t] + gb[t], 0.f);
    float lg[10];
    #pragma unroll
    for (int j = 0; j < 10; ++j){
        float p = v * W3[t*10 + j];
        for (int off = 32; off; off >>= 1) p += __shfl_down(p, off);
        lg[j] = p;
    }
    if (t == 0){
        float m = -3.4e38f;
        #pragma unroll
        for (int j = 0; j < 10; ++j){ lg[j] += b3[j]; m = fmaxf(m, lg[j]); }
        float se = 0.f;
        #pragma unroll
        for (int j = 0; j < 10; ++j) se += expf(lg[j] - m);
        float l = logf(se) + m;
        #pragma unroll
        for (int j = 0; j < 10; ++j) out[r*10 + j] = lg[j] - l;
    }
}

extern "C" void kernel_launch(void* const* d_in, const int* in_sizes, int n_in,
                              void* d_out, int out_size, void* d_ws, size_t ws_size,
                              hipStream_t stream){
    const float* x     = (const float*)d_in[0];
    const float* convW = (const float*)d_in[1];
    const float* convb = (const float*)d_in[2];
    const float* bnW   = (const float*)d_in[3];
    const float* bnB   = (const float*)d_in[4];
    const float* bn7W  = (const float*)d_in[5];
    const float* bn7B  = (const float*)d_in[6];
    const float* attW  = (const float*)d_in[7];
    const float* theta = (const float*)d_in[8];
    const float* lin1W = (const float*)d_in[9];
    const float* lin1b = (const float*)d_in[10];
    const float* lin2W = (const float*)d_in[11];
    const float* lin2b = (const float*)d_in[12];
    const float* lin3W = (const float*)d_in[13];
    const float* lin3b = (const float*)d_in[14];
    const int*   src0  = (const int*)d_in[15];
    const int*   dst0  = (const int*)d_in[16];

    char* base = (char*)d_ws;
    size_t off = 0;
    auto take = [&](size_t bytes) -> void* {
        void* p = base + off;
        off = (off + bytes + 255) & ~(size_t)255;
        return p;
    };
    float* bufGP = (float*)take((size_t)N0G*HF*4);
    float* bufHA = (float*)take((size_t)N0G*HF*4);
    float* bufHB = (float*)take((size_t)(N0G/2)*HF*4);
    int*   srcw  = (int*)  take((size_t)ETOT*4);
    int*   dstw  = (int*)  take((size_t)ETOT*4);
    float* w     = (float*)take((size_t)ETOT*4);
    int2*  csr_p = (int2*) take((size_t)ETOT*8);
    int2*  rb2A  = (int2*) take((size_t)N0G*8);
    int2*  rb2B  = (int2*) take((size_t)N0G*8);
    float* dinvA = (float*)take((size_t)N0G*4);
    float* dinvB = (float*)take((size_t)N0G*4);
    float* st[3];
    st[0] = (float*)take(STSZ*4);
    st[1] = (float*)take(STSZ*4);
    st[2] = (float*)take(STSZ*4);
    float* gacc  = (float*)take((size_t)B_GRAPH*256*4);
    float* t1    = (float*)take((size_t)B_GRAPH*128*4);
    float* t2    = (float*)take((size_t)B_GRAPH*64*4);
    float* statsH= (float*)take(384*4);

    auto coef = [](int kk, float& ca, float& cc){
        double a = 1.0, b = 1.0;
        double c0 = 2.0*kk*(kk+a+b)*(2.0*kk+a+b-2.0);
        double c1 = (2.0*kk+a+b-1.0)*(2.0*kk+a+b)*(2.0*kk+a+b-2.0);
        double c3 = 2.0*(kk+a-1.0)*(kk+b-1.0)*(2.0*kk+a+b);
        ca = (float)(c1/c0); cc = (float)(-c3/c0);
    };
    float ca2, cc2, ca3, cc3;
    coef(2, ca2, cc2);
    coef(3, ca3, cc3);

    k_init_gemm<<<1024 + B_GRAPH, 256, 0, stream>>>(x, convW, bufGP,
                                                    src0, dst0, srcw, dstw, w, csr_p, rb2A, dinvA,
                                                    gacc, statsH, st[0], st[1], st[2]);
    k_prop_stats<<<N0G/8, 256, 0, stream>>>(bufGP, convb, rb2A, csr_p, dinvA, bufHA, st[0], 512, 6, N0G);

    float* G = bufGP + (size_t)4*1024*1024;   // G region for levels >= 1

    for (int i = 0; i < 5; ++i){
        int n = 512 >> i;
        int Nn = B_GRAPH*n;
        int2*  rb_cur = (i & 1) ? rb2B : rb2A;
        int2*  rb_nxt = (i & 1) ? rb2A : rb2B;
        float* dv_cur = (i & 1) ? dinvB : dinvA;
        float* dv_nxt = (i & 1) ? dinvA : dinvB;
        float* Hcur = (i & 1) ? bufHB : bufHA;
        float* Hnxt = (i & 1) ? bufHA : bufHB;
        int wnext = (i < 4) ? (i + 1) : 4;

        k_graph<<<B_GRAPH, 1024, 0, stream>>>(Hcur, st[i % 3], bnW + i*HF, bnB + i*HF, attW + i*HF,
                                              theta + i*4, rb_cur, csr_p, dv_cur,
                                              srcw, dstw, w, bufGP, gacc, rb_nxt, dv_nxt,
                                              st[(i + 2) % 3], st[(i + 1) % 3],
                                              convW + (size_t)wnext*HF*HF, convb + wnext*HF,
                                              G, Hnxt,
                                              lin1W, lin1b, t1, statsH,
                                              1.0f/(float)Nn, ca2, cc2, ca3, cc3, n, (i == 4) ? 1 : 0);
    }

    k_head2<<<B_GRAPH, 128, 0, stream>>>(t1, bnW + 5*HF, bnB + 5*HF, lin2W, lin2b, statsH, t2);
    k_head3<<<B_GRAPH, 64, 0, stream>>>(t2, bn7W, bn7B, lin3W, lin3b, statsH, (float*)d_out);
}